// Round 11
// baseline (488.439 us; speedup 1.0000x reference)
//
#include <hip/hip_runtime.h>
#include <stdint.h>

#define N_TOK 256
#define D_MODEL 1024
#define VOCAB 128000
#define NV_ELEMS (256LL * 128000LL)
#define LIST_CAP 24576      // old fallback sampler
#define GLIST_CAP 16384     // pipeline per-row key list

typedef unsigned long long u64;
typedef uint32_t u32;
typedef __attribute__((ext_vector_type(8))) short bfrag;   // 8 bf16 (4 VGPR)
typedef __attribute__((ext_vector_type(4))) float facc;    // 4 f32

// ===================== helpers =====================
__device__ __forceinline__ uint32_t bf16_rne_bits(float x) {
    uint32_t u = __float_as_uint(x);
    return (u + 0x7fffu + ((u >> 16) & 1u)) >> 16;
}

__device__ __forceinline__ uint32_t rotl32(uint32_t x, int d) {
    return (x << d) | (x >> (32 - d));
}

// monotone key for f32 bits (order-preserving over all finite floats)
__device__ __forceinline__ u32 mono32(u32 b) {
    return (b & 0x80000000u) ? ~b : (b | 0x80000000u);
}
__device__ __forceinline__ float unmono32(u32 k) {
    u32 b = (k & 0x80000000u) ? (k & 0x7FFFFFFFu) : ~k;
    return __uint_as_float(b);
}

// fixed-point mass: rv * 2^30 (u64). max sum ~3e17 << 2^63. deterministic.
__device__ __forceinline__ u64 fixmass(float rv) {
    return (u64)(rv * 1073741824.0f);
}

// JAX threefry2x32, key=(0,42) (KAT-verified core)
__device__ __forceinline__ uint2 tf_0_42(uint32_t c0, uint32_t c1) {
    const uint32_t ks0 = 0u, ks1 = 42u, ks2 = 0x1BD11BDAu ^ 42u;
    uint32_t x0 = c0 + ks0, x1 = c1 + ks1;
#define R4(a,b,c,d) \
    x0 += x1; x1 = rotl32(x1,a); x1 ^= x0; \
    x0 += x1; x1 = rotl32(x1,b); x1 ^= x0; \
    x0 += x1; x1 = rotl32(x1,c); x1 ^= x0; \
    x0 += x1; x1 = rotl32(x1,d); x1 ^= x0;
    R4(13,15,26,6)   x0 += ks1; x1 += ks2 + 1u;
    R4(17,29,16,24)  x0 += ks2; x1 += ks0 + 2u;
    R4(13,15,26,6)   x0 += ks0; x1 += ks1 + 3u;
    R4(17,29,16,24)  x0 += ks1; x1 += ks2 + 4u;
    R4(13,15,26,6)   x0 += ks2; x1 += ks0 + 5u;
#undef R4
    return make_uint2(x0, x1);
}

// partitionable threefry bits: counter=(0,j), out = x^y (verified r3)
__device__ __forceinline__ uint32_t jax_bits(uint32_t j) {
    uint2 r = tf_0_42(0u, j);
    return r.x ^ r.y;
}

__device__ __forceinline__ float jax_gumbel(uint32_t bits) {
    const float TINY = 1.17549435e-38f;
    float u = __uint_as_float((bits >> 9) | 0x3f800000u) - 1.0f;
    u = u + TINY;
    u = fmaxf(TINY, u);
    return -__logf(-__logf(u));
}

__device__ __forceinline__ float rv_of(float l, float rinv) {
    return __expf(l * rinv);
}

// async 16B global->LDS (dest = lbase + lane*16)
__device__ __forceinline__ void async_copy16(const void* g, void* lbase, int lane) {
#if defined(__has_builtin) && __has_builtin(__builtin_amdgcn_global_load_lds)
    __builtin_amdgcn_global_load_lds((const uint32_t*)g, (uint32_t*)lbase, 16, 0, 0);
#else
    *(bfrag*)((char*)lbase + lane * 16) = *(const bfrag*)g;
#endif
}

// descending-bucket scan, one wave (lanes 0..63), exact u64 arithmetic
__device__ __forceinline__ void scan_desc_u64(const u64* h, int nb, u64 carry, u64 P,
                                              int* outCb, u64* outSa) {
    int lane = (int)threadIdx.x & 63;
    int chunk = nb >> 6;
    int top = nb - 1 - lane * chunk;
    u64 ls = 0ull;
    for (int j = 0; j < chunk; ++j) ls += h[top - j];
    u64 incl = ls;
    for (int o = 1; o < 64; o <<= 1) {
        u64 v = __shfl_up(incl, o, 64);
        if (lane >= o) incl += v;
    }
    u64 s0 = carry + incl - ls;
    unsigned long long mask = __ballot(s0 + ls > P);
    if (mask == 0ull) {
        if (lane == 0) { *outCb = 0; *outSa = carry; }   // cannot happen (P < total)
    } else {
        int cstar = (int)__builtin_ctzll(mask);
        if (lane == cstar) {
            u64 sa = s0; int cb = 0;
            for (int j = 0; j < chunk; ++j) {
                int b = top - j;
                if (sa + h[b] > P) { cb = b; break; }
                sa += h[b];
            }
            *outCb = cb; *outSa = sa;
        }
    }
}

// ============ A pre-convert (gather + split-bf16 + swizzled image, BK=32) ====
__global__ __launch_bounds__(256) void prep_a(
        const float* __restrict__ hidden, const int* __restrict__ idx,
        ushort* __restrict__ wsA) {
    const int m = blockIdx.x;
    const int t = threadIdx.x;
    const float* src = hidden + (long long)idx[m] * D_MODEL;
    const uint32_t swz = (uint32_t)((m & 7) << 4);
    for (int j = 0; j < 4; ++j) {
        int k = t * 4 + j;
        float x = src[k];
        uint32_t hb = bf16_rne_bits(x);
        float hf = __uint_as_float(hb << 16);
        uint32_t lb = bf16_rne_bits(x - hf);
        int kt = k >> 5, kk = k & 31, g = kk >> 3, e = kk & 7;
        char* img = (char*)wsA + (size_t)kt * 32768;
        uint32_t base = (uint32_t)(m * 128 + g * 32);
        *(ushort*)(img + ((base + 0) ^ swz) + e * 2) = (ushort)hb;
        *(ushort*)(img + ((base + 16) ^ swz) + e * 2) = (ushort)lb;
    }
}

// B tile convert+write helper: 8 f32 -> bf16 hi/lo, swizzled b128 LDS writes
__device__ __forceinline__ void bconv_write(char* Bb, float4 x0, float4 x1,
                                            int rb, int g) {
    float xs[8] = {x0.x, x0.y, x0.z, x0.w, x1.x, x1.y, x1.z, x1.w};
    bfrag h, lo;
#pragma unroll
    for (int e = 0; e < 8; ++e) {
        uint32_t hb = bf16_rne_bits(xs[e]);
        float hf = __uint_as_float(hb << 16);
        uint32_t lb = bf16_rne_bits(xs[e] - hf);
        h[e] = (short)hb; lo[e] = (short)lb;
    }
    uint32_t swz = (uint32_t)((rb & 7) << 4);
    uint32_t base = (uint32_t)(rb * 128 + g * 32);
    *(bfrag*)(Bb + ((base + 0) ^ swz)) = h;
    *(bfrag*)(Bb + ((base + 16) ^ swz)) = lo;
}

// ===== split-bf16 MFMA GEMM (BM=256,BN=64,BK=32, 4 waves) — 2-phase LDS
// double-buffer: issue stage(k+1) BEFORE MFMA(k); barrier drain lands AFTER
// the overlap window (m97-stall avoidance). 80 KB LDS -> 2 blocks/CU. =====
__global__ __launch_bounds__(256) void gemm_mfma(
        const ushort* __restrict__ wsA, const float* __restrict__ emb,
        float* __restrict__ logits) {
    __shared__ __align__(16) ushort Aimg[2][16384];  // 2 x 32 KB
    __shared__ __align__(16) ushort Bimg[2][4096];   // 2 x 8 KB
    const int tid = (int)threadIdx.x;
    const int w = tid >> 6, l = tid & 63;
    const int lr = l & 15, lg = l >> 4;
    const int v0 = blockIdx.x * 64;

    facc acc[4][4] = {};

    const int rb = tid >> 2, g = tid & 3;
    const float* bbase = emb + (size_t)(v0 + rb) * D_MODEL + g * 8;

    // prologue: stage tile 0 into buffer 0
    {
        const char* asrc = (const char*)wsA;
#pragma unroll
        for (int i = 0; i < 8; ++i) {
            int off = w * 8192 + i * 1024;
            async_copy16(asrc + off + l * 16, (char*)Aimg[0] + off, l);
        }
        float4 x0 = *(const float4*)(bbase);
        float4 x1 = *(const float4*)(bbase + 4);
        bconv_write((char*)Bimg[0], x0, x1, rb, g);
    }
    __syncthreads();

    for (int kt = 0; kt < 32; ++kt) {
        const int cur = kt & 1, nxt = cur ^ 1;
        // issue next-tile staging EARLY (flies during MFMA below)
        float4 n0 = {}, n1 = {};
        if (kt < 31) {
            const char* asrc = (const char*)wsA + (size_t)(kt + 1) * 32768;
#pragma unroll
            for (int i = 0; i < 8; ++i) {
                int off = w * 8192 + i * 1024;
                async_copy16(asrc + off + l * 16, (char*)Aimg[nxt] + off, l);
            }
            n0 = *(const float4*)(bbase + (kt + 1) * 32);
            n1 = *(const float4*)(bbase + (kt + 1) * 32 + 4);
        }
        // MFMA on current buffer
        char* Ab = (char*)Aimg[cur];
        char* Bb = (char*)Bimg[cur];
        bfrag bh[4], bl[4];
#pragma unroll
        for (int nj = 0; nj < 4; ++nj) {
            int rbf = nj * 16 + lr;
            uint32_t swz = (uint32_t)((rbf & 7) << 4);
            uint32_t base = (uint32_t)(rbf * 128 + lg * 32);
            bh[nj] = *(const bfrag*)(Bb + ((base + 0) ^ swz));
            bl[nj] = *(const bfrag*)(Bb + ((base + 16) ^ swz));
        }
#pragma unroll
        for (int mi = 0; mi < 4; ++mi) {
            int r = w * 64 + mi * 16 + lr;
            uint32_t swz = (uint32_t)((r & 7) << 4);
            uint32_t base = (uint32_t)(r * 128 + lg * 32);
            bfrag ah = *(const bfrag*)(Ab + ((base + 0) ^ swz));
            bfrag al = *(const bfrag*)(Ab + ((base + 16) ^ swz));
#pragma unroll
            for (int nj = 0; nj < 4; ++nj) {
                acc[mi][nj] = __builtin_amdgcn_mfma_f32_16x16x32_bf16(ah, bh[nj], acc[mi][nj], 0, 0, 0);
                acc[mi][nj] = __builtin_amdgcn_mfma_f32_16x16x32_bf16(ah, bl[nj], acc[mi][nj], 0, 0, 0);
                acc[mi][nj] = __builtin_amdgcn_mfma_f32_16x16x32_bf16(al, bh[nj], acc[mi][nj], 0, 0, 0);
            }
        }
        // convert next B (reg wait happens here, AFTER the MFMA overlap window)
        if (kt < 31) bconv_write((char*)Bimg[nxt], n0, n1, rb, g);
        __syncthreads();
    }
    // C write: row = w*64 + mi*16 + lg*4 + reg, col = v0 + nj*16 + lr
#pragma unroll
    for (int mi = 0; mi < 4; ++mi) {
        int mbase = w * 64 + mi * 16 + lg * 4;
#pragma unroll
        for (int nj = 0; nj < 4; ++nj) {
            int v = v0 + nj * 16 + lr;
#pragma unroll
            for (int reg = 0; reg < 4; ++reg)
                logits[(size_t)(mbase + reg) * VOCAB + v] = acc[mi][nj][reg];
        }
    }
}

// ===================== f32 GEMM fallback (ws too small) =====================
__global__ __launch_bounds__(256) void gemm_kernel(
        const float* __restrict__ hidden, const int* __restrict__ idx,
        const float* __restrict__ emb, float* __restrict__ logits) {
    __shared__ float As[16][64];
    __shared__ float Bs[16][64];
    const int n0 = blockIdx.x * 64, v0 = blockIdx.y * 64;
    const int tid = threadIdx.x;
    const int tx = tid & 15, ty = tid >> 4;
    const int lr = tid >> 2, lk = (tid & 3) * 4;
    float acc[4][4] = {};
    const long long aRow = (long long)idx[n0 + lr] * D_MODEL + lk;
    const long long bRow = (long long)(v0 + lr) * D_MODEL + lk;
    for (int k0 = 0; k0 < D_MODEL; k0 += 16) {
        float4 av = *(const float4*)(hidden + aRow + k0);
        float4 bv = *(const float4*)(emb + bRow + k0);
        __syncthreads();
        As[lk + 0][lr] = av.x; As[lk + 1][lr] = av.y; As[lk + 2][lr] = av.z; As[lk + 3][lr] = av.w;
        Bs[lk + 0][lr] = bv.x; Bs[lk + 1][lr] = bv.y; Bs[lk + 2][lr] = bv.z; Bs[lk + 3][lr] = bv.w;
        __syncthreads();
#pragma unroll
        for (int kk = 0; kk < 16; ++kk) {
            float4 a = *(const float4*)&As[kk][ty * 4];
            float4 b = *(const float4*)&Bs[kk][tx * 4];
            float aa[4] = {a.x, a.y, a.z, a.w};
            float bb[4] = {b.x, b.y, b.z, b.w};
#pragma unroll
            for (int i = 0; i < 4; ++i)
#pragma unroll
                for (int j = 0; j < 4; ++j)
                    acc[i][j] += aa[i] * bb[j];
        }
    }
#pragma unroll
    for (int i = 0; i < 4; ++i) {
        float4 o = make_float4(acc[i][0], acc[i][1], acc[i][2], acc[i][3]);
        *(float4*)(logits + (long long)(n0 + ty * 4 + i) * VOCAB + (v0 + tx * 4)) = o;
    }
}

// ===================== sampler pipeline (6 kernels) =====================
// K1: per-row-quarter L1 histogram -> NON-ATOMIC per-block partial slice
//     (no memset needed; slices live in the 'list' region, time-disjoint)
__global__ __launch_bounds__(512) void hist1_kernel(
        const float* __restrict__ probs, const float* __restrict__ temps,
        u64* __restrict__ hpart) {
    const int row = blockIdx.y, hb = blockIdx.x, tid = (int)threadIdx.x;
    __shared__ u64 h[4096];
    for (int i = tid; i < 4096; i += 512) h[i] = 0ull;
    __syncthreads();
    const float rinv = 1.0f / temps[row];
    const float4* R4 = (const float4*)(probs + (size_t)row * VOCAB);
    const int base4 = hb * 8000;
    for (int i = 0; i < 16; ++i) {
        int j = tid + i * 512;
        if (j < 8000) {
            float4 x = R4[base4 + j];
            float xs[4] = {x.x, x.y, x.z, x.w};
#pragma unroll
            for (int c = 0; c < 4; ++c) {
                u32 key = mono32(__float_as_uint(xs[c]));
                atomicAdd(&h[key >> 20], fixmass(rv_of(xs[c], rinv)));
            }
        }
    }
    __syncthreads();
    u64* gh = hpart + ((size_t)row * 4 + hb) * 4096;
    for (int i = tid; i < 4096; i += 512) gh[i] = h[i];   // full overwrite
}

// K2: sum 4 partial slices in LDS, exact u64 descending scan; also zeroes
//     listCnt/argmax for the downstream kernels (replaces memsets)
__global__ __launch_bounds__(64) void scan1_kernel(
        const u64* __restrict__ hpart, const float* __restrict__ topps,
        u64* __restrict__ rsP, u64* __restrict__ rsCarry, u32* __restrict__ rsCb,
        u32* __restrict__ listCnt, u64* __restrict__ argmax) {
    const int row = blockIdx.x, lane = (int)threadIdx.x;
    __shared__ u64 sh[4096];
    const u64* hp = hpart + (size_t)row * 4 * 4096;
    u64 S = 0ull;
    for (int j = lane; j < 4096; j += 64) {
        u64 v = hp[j] + hp[4096 + j] + hp[8192 + j] + hp[12288 + j];
        sh[j] = v;
        S += v;
    }
    __syncthreads();
    for (int o = 32; o >= 1; o >>= 1) S += __shfl_xor(S, o, 64);
    const u64 P = (u64)((double)topps[row] * (double)S);
    __shared__ int sCb; __shared__ u64 sSa;
    scan_desc_u64(sh, 4096, 0ull, P, &sCb, &sSa);
    __syncthreads();
    if (lane == 0) {
        rsP[row] = P; rsCarry[row] = sSa; rsCb[row] = (u32)sCb;
        listCnt[row] = 0u; argmax[row] = 0ull;
    }
}

// K3: compact (key, idx) of cut L1 bucket -> per-row list (LDS-staged, G12)
__global__ __launch_bounds__(512) void compact_kernel(
        const float* __restrict__ probs, const u32* __restrict__ rsCb,
        u64* __restrict__ list, u32* __restrict__ listCnt) {
    const int row = blockIdx.y, hb = blockIdx.x, tid = (int)threadIdx.x;
    __shared__ u64 buf[4096];
    __shared__ u32 lcnt, gbase;
    const u32 cb1 = rsCb[row];
    const float4* R4 = (const float4*)(probs + (size_t)row * VOCAB);
    u64* lst = list + (size_t)row * GLIST_CAP;
    const int base4 = hb * 8000;
    if (tid == 0) lcnt = 0u;
    __syncthreads();
    for (int pair = 0; pair < 8; ++pair) {
#pragma unroll
        for (int s = 0; s < 2; ++s) {
            int j = tid + (pair * 2 + s) * 512;
            if (j < 8000) {
                float4 x = R4[base4 + j];
                float xs[4] = {x.x, x.y, x.z, x.w};
#pragma unroll
                for (int c = 0; c < 4; ++c) {
                    u32 key = mono32(__float_as_uint(xs[c]));
                    if ((key >> 20) == cb1) {
                        u32 pos = atomicAdd(&lcnt, 1u);
                        buf[pos] = ((u64)key << 32) | (u32)((base4 + j) * 4 + c);
                    }
                }
            }
        }
        __syncthreads();
        u32 n = lcnt;
        if (n) {
            if (tid == 0) gbase = atomicAdd(&listCnt[row], n);
            __syncthreads();
            u32 gb = gbase;
            for (u32 i2 = tid; i2 < n; i2 += 512) {
                u32 gpos = gb + i2;
                if (gpos < GLIST_CAP) lst[gpos] = buf[i2];
            }
        }
        __syncthreads();
        if (tid == 0) lcnt = 0u;
        __syncthreads();
    }
}

// K4: in-LDS L2/L3 refinement over the compacted list -> exact ts, mt, Sp, ties
__global__ __launch_bounds__(1024) void resolve_kernel(
        const u64* __restrict__ list, const u32* __restrict__ listCnt,
        const u64* __restrict__ rsP, const u64* __restrict__ rsCarry,
        const u32* __restrict__ rsCb, const float* __restrict__ temps,
        u32* __restrict__ scTs, u32* __restrict__ scTieN,
        float* __restrict__ scInvSp, u32* __restrict__ tieKept) {
    const int row = blockIdx.x, tid = (int)threadIdx.x;
    __shared__ u64 h2[1024];
    __shared__ u32 c3[1024];
    __shared__ int sCb; __shared__ u64 sSa;
    __shared__ u32 sTc;
    __shared__ u32 tlist[1024];
    const u32 cnt = min(listCnt[row], (u32)GLIST_CAP);
    const u64 P = rsP[row];
    const float rinv = 1.0f / temps[row];
    const u64* lst = list + (size_t)row * GLIST_CAP;

    h2[tid] = 0ull;
    __syncthreads();
    for (u32 j = tid; j < cnt; j += 1024) {
        u32 key = (u32)(lst[j] >> 32);
        atomicAdd(&h2[(key >> 10) & 1023u], fixmass(rv_of(unmono32(key), rinv)));
    }
    __syncthreads();
    if (tid < 64) scan_desc_u64(h2, 1024, rsCarry[row], P, &sCb, &sSa);
    __syncthreads();
    const u32 cb2 = (u32)sCb; const u64 carry2 = sSa;
    __syncthreads();

    h2[tid] = 0ull; c3[tid] = 0u;
    __syncthreads();
    for (u32 j = tid; j < cnt; j += 1024) {
        u32 key = (u32)(lst[j] >> 32);
        if (((key >> 10) & 1023u) == cb2) {
            atomicAdd(&h2[key & 1023u], fixmass(rv_of(unmono32(key), rinv)));
            atomicAdd(&c3[key & 1023u], 1u);
        }
    }
    __syncthreads();
    if (tid < 64) scan_desc_u64(h2, 1024, carry2, P, &sCb, &sSa);
    __syncthreads();
    const int cb3 = sCb; const u64 sa3 = sSa;
    const u32 ts = (rsCb[row] << 20) | (cb2 << 10) | (u32)cb3;
    u32 cntb = c3[cb3]; if (cntb == 0u) cntb = 1u;
    const u64 tfq = fixmass(rv_of(unmono32(ts), rinv));
    const u64 rem = P - sa3;
    u32 mt;
    if (tfq == 0ull) mt = cntb;
    else {
        u64 q = rem / tfq;
        mt = (q >= (u64)(cntb - 1)) ? cntb : ((u32)q + 1u);
    }
    const u64 Spq = sa3 + (u64)mt * tfq;

    if (tid == 0) sTc = 0u;
    __syncthreads();
    for (u32 j = tid; j < cnt; j += 1024) {
        if ((u32)(lst[j] >> 32) == ts) {
            u32 pos = atomicAdd(&sTc, 1u);
            if (pos < 1024u) tlist[pos] = (u32)lst[j];
        }
    }
    __syncthreads();
    const u32 tn = min(sTc, 1024u);
    if ((u32)tid < tn) {
        u32 my = tlist[tid];
        u32 rank = 0;
        for (u32 j2 = 0; j2 < tn; ++j2) rank += (tlist[j2] < my) ? 1u : 0u;
        if (rank < mt) tieKept[(size_t)row * 1024 + rank] = my;
    }
    if (tid == 0) {
        scTs[row] = ts;
        scTieN[row] = min(mt, tn);
        scInvSp[row] = (float)(1073741824.0 / (double)Spq);
    }
}

// K5: write probs_f + gumbel-argmax (exp/gumbel only for kept elems)
__global__ __launch_bounds__(512) void final2_kernel(
        float* __restrict__ probs, const float* __restrict__ temps,
        const u32* __restrict__ scTs, const u32* __restrict__ scTieN,
        const float* __restrict__ scInvSp, const u32* __restrict__ tieKept,
        u64* __restrict__ argmax) {
    const int row = blockIdx.y, hb = blockIdx.x, tid = (int)threadIdx.x;
    __shared__ u32 tl[1024];
    __shared__ u64 wbest[8];
    const u32 ts = scTs[row], tieN = scTieN[row];
    const float invSp = scInvSp[row];
    const float rinv = 1.0f / temps[row];
    for (u32 i = tid; i < tieN; i += 512) tl[i] = tieKept[(size_t)row * 1024 + i];
    __syncthreads();
    float4* R4 = (float4*)(probs + (size_t)row * VOCAB);
    const u32 rowBase = (u32)row * (u32)VOCAB;
    const int base4 = hb * 8000;
    u64 best = 0ull;
    for (int i = 0; i < 16; ++i) {
        int j = tid + i * 512;
        if (j < 8000) {
            float4 x = R4[base4 + j];
            float xs[4] = {x.x, x.y, x.z, x.w};
            float4 out;
            float* op = (float*)&out;
#pragma unroll
            for (int c = 0; c < 4; ++c) {
                u32 key = mono32(__float_as_uint(xs[c]));
                u32 v = (u32)((base4 + j) * 4 + c);
                bool kept = key > ts;
                if (key == ts) {
                    kept = false;
                    for (u32 q2 = 0; q2 < tieN; ++q2)
                        if (tl[q2] == v) { kept = true; break; }
                }
                if (kept) {
                    float pf = rv_of(xs[c], rinv) * invSp;
                    op[c] = pf;
                    float g = jax_gumbel(jax_bits(rowBase + v));
                    float val = __logf(pf + 1e-20f) + g;
                    u64 pk = ((u64)mono32(__float_as_uint(val)) << 32) | (u32)(~v);
                    if (pk > best) best = pk;
                } else {
                    op[c] = 0.0f;
                }
            }
            R4[base4 + j] = out;
        }
    }
    for (int o = 32; o >= 1; o >>= 1) {
        u64 ob = __shfl_xor(best, o, 64);
        if (ob > best) best = ob;
    }
    if ((tid & 63) == 0) wbest[tid >> 6] = best;
    __syncthreads();
    if (tid == 0) {
        u64 b = wbest[0];
        for (int w2 = 1; w2 < 8; ++w2) if (wbest[w2] > b) b = wbest[w2];
        atomicMax(&argmax[row], b);
    }
}

// K6: token write
__global__ void token_kernel(const u64* __restrict__ argmax, float* __restrict__ outTok) {
    int n = (int)threadIdx.x;
    if (n < N_TOK) outTok[n] = (float)(~(u32)argmax[n]);
}

// ============== OLD fused per-row sampler (r5 verified; ws fallback) ========
__device__ __forceinline__ void scan_desc_wave(const float* h, int nb, float carry,
                                               float P, int* outCb, float* outSa) {
    int lane = (int)threadIdx.x & 63;
    int chunk = nb >> 6;
    int top = nb - 1 - lane * chunk;
    float ls = 0.0f;
    for (int j = 0; j < chunk; ++j) ls += h[top - j];
    float incl = ls;
    for (int o = 1; o < 64; o <<= 1) {
        float v = __shfl_up(incl, o, 64);
        if (lane >= o) incl += v;
    }
    float s0 = carry + incl - ls;
    unsigned long long mask = __ballot(s0 + ls > P);
    if (mask == 0ull) {
        if (lane == 63) { *outCb = 0; *outSa = carry + incl - h[0]; }
    } else {
        int cstar = (int)__builtin_ctzll(mask);
        if (lane == cstar) {
            float sa = s0; int cb = 0;
            for (int j = 0; j < chunk; ++j) {
                int b = top - j;
                if (sa + h[b] > P) { cb = b; break; }
                sa += h[b];
            }
            *outCb = cb; *outSa = sa;
        }
    }
}

__global__ __launch_bounds__(1024) void sample_kernel(
        float* __restrict__ probs, const float* __restrict__ temps,
        const float* __restrict__ topps, float* __restrict__ outTok) {
    const int row = blockIdx.x;
    const int tid = (int)threadIdx.x;
    float* L = probs + (long long)row * VOCAB;
    const float4* L4 = (const float4*)L;
    float4* L4w = (float4*)L;

    __shared__ float waveH[16][2048];
    __shared__ float hsum[2048];
    __shared__ uint32_t hcnt[1024];
    __shared__ float wred[16];
    __shared__ float aVal[16];
    __shared__ int aIdx[16];
    __shared__ uint32_t tieList[256];
    __shared__ int sCb;
    __shared__ float sSa;
    __shared__ float sP, sCarry1, sCarry2, sSp, sInvSp;
    __shared__ uint32_t sPref1, sCb2, sTsKey, sMt, sTieN, sCnt;
    uint32_t* keys = (uint32_t*)&waveH[4][0];

    const float t = temps[row];
    const float p = topps[row];
    const float rinv = 1.0f / t;

    for (int i = tid; i < 16 * 2048; i += 1024) ((float*)waveH)[i] = 0.0f;
    __syncthreads();
    {
        float* myH = waveH[tid >> 6];
#pragma unroll 2
        for (int i = 0; i < 31; ++i) {
            float4 x = L4[tid + i * 1024];
            float r0 = rv_of(x.x, rinv), r1 = rv_of(x.y, rinv);
            float r2 = rv_of(x.z, rinv), r3 = rv_of(x.w, rinv);
            atomicAdd(&myH[__float_as_uint(r0) >> 20], r0);
            atomicAdd(&myH[__float_as_uint(r1) >> 20], r1);
            atomicAdd(&myH[__float_as_uint(r2) >> 20], r2);
            atomicAdd(&myH[__float_as_uint(r3) >> 20], r3);
        }
        if (tid < 256) {
            float4 x = L4[31744 + tid];
            float r0 = rv_of(x.x, rinv), r1 = rv_of(x.y, rinv);
            float r2 = rv_of(x.z, rinv), r3 = rv_of(x.w, rinv);
            atomicAdd(&myH[__float_as_uint(r0) >> 20], r0);
            atomicAdd(&myH[__float_as_uint(r1) >> 20], r1);
            atomicAdd(&myH[__float_as_uint(r2) >> 20], r2);
            atomicAdd(&myH[__float_as_uint(r3) >> 20], r3);
        }
    }
    __syncthreads();
    {
        float a0 = 0.0f, a1 = 0.0f;
#pragma unroll
        for (int w2 = 0; w2 < 16; ++w2) { a0 += waveH[w2][tid]; a1 += waveH[w2][tid + 1024]; }
        hsum[tid] = a0; hsum[tid + 1024] = a1;
        float s = a0 + a1;
        for (int o = 32; o >= 1; o >>= 1) s += __shfl_xor(s, o, 64);
        if ((tid & 63) == 0) wred[tid >> 6] = s;
    }
    __syncthreads();
    if (tid == 0) {
        float tot = 0.0f;
        for (int w2 = 0; w2 < 16; ++w2) tot += wred[w2];
        sP = p * tot;
    }
    __syncthreads();
    if (tid < 64) scan_desc_wave(hsum, 2048, 0.0f, sP, &sCb, &sSa);
    __syncthreads();
    if (tid == 0) { sPref1 = (uint32_t)sCb; sCarry1 = sSa; sCnt = 0u; }
    __syncthreads();

    const uint32_t pref1 = sPref1;
    const float P = sP;
#pragma unroll 2
    for (int i = 0; i < 31; ++i) {
        float4 x = L4[tid + i * 1024];
        float rr[4] = {rv_of(x.x, rinv), rv_of(x.y, rinv), rv_of(x.z, rinv), rv_of(x.w, rinv)};
#pragma unroll
        for (int c = 0; c < 4; ++c) {
            uint32_t key = __float_as_uint(rr[c]);
            if ((key >> 20) == pref1) {
                uint32_t pos = atomicAdd(&sCnt, 1u);
                if (pos < LIST_CAP) keys[pos] = key;
            }
        }
    }
    if (tid < 256) {
        float4 x = L4[31744 + tid];
        float rr[4] = {rv_of(x.x, rinv), rv_of(x.y, rinv), rv_of(x.z, rinv), rv_of(x.w, rinv)};
#pragma unroll
        for (int c = 0; c < 4; ++c) {
            uint32_t key = __float_as_uint(rr[c]);
            if ((key >> 20) == pref1) {
                uint32_t pos = atomicAdd(&sCnt, 1u);
                if (pos < LIST_CAP) keys[pos] = key;
            }
        }
    }
    __syncthreads();
    const uint32_t K = sCnt;
    const bool inLds = (K <= LIST_CAP);

    if (tid < 1024) hsum[tid] = 0.0f;
    __syncthreads();
    if (inLds) {
        for (uint32_t j = tid; j < K; j += 1024) {
            uint32_t key = keys[j];
            atomicAdd(&hsum[(key >> 10) & 1023u], __uint_as_float(key));
        }
    } else {
        for (int i = 0; i < 125; ++i) {
            int v = tid + i * 1024;
            float rv = rv_of(L[v], rinv);
            uint32_t key = __float_as_uint(rv);
            if ((key >> 20) == pref1) atomicAdd(&hsum[(key >> 10) & 1023u], rv);
        }
    }
    __syncthreads();
    if (tid < 64) scan_desc_wave(hsum, 1024, sCarry1, P, &sCb, &sSa);
    __syncthreads();
    if (tid == 0) { sCb2 = (uint32_t)sCb; sCarry2 = sSa; }
    __syncthreads();

    const uint32_t cb2 = sCb2;
    if (tid < 1024) { hsum[tid] = 0.0f; hcnt[tid] = 0u; }
    __syncthreads();
    if (inLds) {
        for (uint32_t j = tid; j < K; j += 1024) {
            uint32_t key = keys[j];
            if (((key >> 10) & 1023u) == cb2) {
                atomicAdd(&hsum[key & 1023u], __uint_as_float(key));
                atomicAdd(&hcnt[key & 1023u], 1u);
            }
        }
    } else {
        const uint32_t pref2full = (pref1 << 10) | cb2;
        for (int i = 0; i < 125; ++i) {
            int v = tid + i * 1024;
            float rv = rv_of(L[v], rinv);
            uint32_t key = __float_as_uint(rv);
            if ((key >> 10) == pref2full) {
                atomicAdd(&hsum[key & 1023u], rv);
                atomicAdd(&hcnt[key & 1023u], 1u);
            }
        }
    }
    __syncthreads();
    if (tid < 64) scan_desc_wave(hsum, 1024, sCarry2, P, &sCb, &sSa);
    __syncthreads();
    if (tid == 0) {
        int cb3 = sCb; float sa3 = sSa;
        uint32_t ts = (pref1 << 20) | (cb2 << 10) | (uint32_t)cb3;
        uint32_t cnt = hcnt[cb3]; if (cnt == 0u) cnt = 1u;
        float tf = __uint_as_float(ts);
        uint32_t mt;
        float rem = P - sa3; if (rem < 0.0f) rem = 0.0f;
        if (!(tf > 0.0f)) mt = cnt;
        else {
            float q = floorf(rem / tf);
            mt = (q >= (float)(cnt - 1)) ? cnt : ((uint32_t)q + 1u);
        }
        sTsKey = ts; sMt = mt;
        sSp = sa3 + (float)mt * tf;
        sInvSp = 1.0f / sSp;
        sTieN = 0u;
    }
    __syncthreads();

    const uint32_t ts = sTsKey, mt = sMt;
    const float invSp = sInvSp;
    float bestV = -INFINITY;
    int bestI = 0x7FFFFFFF;
    const uint32_t rowBase = (uint32_t)row * (uint32_t)VOCAB;
    for (int i = 0; i < 32; ++i) {
        int f4i = (i < 31) ? (tid + i * 1024) : (31744 + tid);
        if (i == 31 && tid >= 256) break;
        float4 x = L4[f4i];
        float rr[4] = {rv_of(x.x, rinv), rv_of(x.y, rinv), rv_of(x.z, rinv), rv_of(x.w, rinv)};
        float4 out;
        float* op = (float*)&out;
#pragma unroll
        for (int c = 0; c < 4; ++c) {
            uint32_t key = __float_as_uint(rr[c]);
            int v = f4i * 4 + c;
            if (key > ts) {
                float pf = rr[c] * invSp;
                op[c] = pf;
                float g = jax_gumbel(jax_bits(rowBase + (uint32_t)v));
                float val = __logf(pf + 1e-20f) + g;
                if (val > bestV || (val == bestV && v < bestI)) { bestV = val; bestI = v; }
            } else if (key == ts) {
                op[c] = 0.0f;
                uint32_t pos = atomicAdd(&sTieN, 1u);
                if (pos < 256u) tieList[pos] = (uint32_t)v;
            } else {
                op[c] = 0.0f;
            }
        }
        L4w[f4i] = out;
    }
    __syncthreads();
    {
        const uint32_t tn = min(sTieN, 256u);
        if ((uint32_t)tid < tn) {
            uint32_t v = tieList[tid];
            uint32_t rank = 0;
            for (uint32_t j = 0; j < tn; ++j) rank += (tieList[j] < v) ? 1u : 0u;
            if (rank < mt) {
                float pf = __uint_as_float(ts) * invSp;
                L[v] = pf;
                float g = jax_gumbel(jax_bits(rowBase + v));
                float val = __logf(pf + 1e-20f) + g;
                if (val > bestV || (val == bestV && (int)v < bestI)) { bestV = val; bestI = (int)v; }
            }
        }
    }
    for (int o = 32; o >= 1; o >>= 1) {
        float ov = __shfl_xor(bestV, o, 64);
        int oi = __shfl_xor(bestI, o, 64);
        if (ov > bestV || (ov == bestV && oi < bestI)) { bestV = ov; bestI = oi; }
    }
    if ((tid & 63) == 0) { aVal[tid >> 6] = bestV; aIdx[tid >> 6] = bestI; }
    __syncthreads();
    if (tid == 0) {
        float bv = aVal[0]; int bi = aIdx[0];
        for (int w2 = 1; w2 < 16; ++w2) {
            if (aVal[w2] > bv || (aVal[w2] == bv && aIdx[w2] < bi)) { bv = aVal[w2]; bi = aIdx[w2]; }
        }
        outTok[row] = (float)bi;
    }
}

// ===================== launch =====================
extern "C" void kernel_launch(void* const* d_in, const int* in_sizes, int n_in,
                              void* d_out, int out_size, void* d_ws, size_t ws_size,
                              hipStream_t stream) {
    const float* hidden = (const float*)d_in[0];
    const float* emb    = (const float*)d_in[1];
    const float* temps  = (const float*)d_in[2];
    const float* topps  = (const float*)d_in[3];
    const int*   idx    = (const int*)d_in[4];

    float* probs  = (float*)d_out;        // [N,V]: logits, then probs_f in place
    float* outTok = probs + NV_ELEMS;     // [N] tokens as f32

    char* ws = (char*)d_ws;
    const bool wsGemm = ws_size >= (size_t)(1u << 20);
    const bool wsBig  = ws_size >= (size_t)(44u << 20);

    if (wsGemm) {
        ushort* wsA = (ushort*)ws;        // 32 x 32 KB pre-swizzled A images
        prep_a<<<N_TOK, 256, 0, stream>>>(hidden, idx, wsA);
        gemm_mfma<<<VOCAB / 64, 256, 0, stream>>>(wsA, emb, probs);
    } else {
        gemm_kernel<<<dim3(4, 2000), 256, 0, stream>>>(hidden, idx, emb, probs);
    }

    if (wsBig) {
        // layout: [0,1MB) wsA | [9MB,41MB) list region (doubles as hist1
        // partial slices: 256 rows x 4 blocks x 4096 u64 = 32MB, time-disjoint
        // with the compacted list) | [41MB,..) small state | tieKept 1MB
        u64* list      = (u64*)(ws + (9u << 20));
        char* m        = ws + (41u << 20);
        u32* listCnt   = (u32*)(m);                 // 1 KB
        u32* rsCb      = (u32*)(m + 1024);          // 1 KB
        u64* rsP       = (u64*)(m + 2048);          // 2 KB
        u64* rsCarry   = (u64*)(m + 4096);          // 2 KB
        u32* scTs      = (u32*)(m + 6144);          // 1 KB
        u32* scTieN    = (u32*)(m + 7168);          // 1 KB
        float* scInvSp = (float*)(m + 8192);        // 1 KB
        u64* argmax    = (u64*)(m + 9216);          // 2 KB
        u32* tieKept   = (u32*)(m + 16384);         // 1 MB

        hist1_kernel<<<dim3(4, N_TOK), 512, 0, stream>>>(probs, temps, list);
        scan1_kernel<<<N_TOK, 64, 0, stream>>>(list, topps, rsP, rsCarry, rsCb,
                                               listCnt, argmax);
        compact_kernel<<<dim3(4, N_TOK), 512, 0, stream>>>(probs, rsCb, list, listCnt);
        resolve_kernel<<<N_TOK, 1024, 0, stream>>>(list, listCnt, rsP, rsCarry, rsCb,
                                                   temps, scTs, scTieN, scInvSp, tieKept);
        final2_kernel<<<dim3(4, N_TOK), 512, 0, stream>>>(probs, temps, scTs, scTieN,
                                                          scInvSp, tieKept, argmax);
        token_kernel<<<1, 256, 0, stream>>>(argmax, outTok);
    } else {
        sample_kernel<<<N_TOK, 1024, 0, stream>>>(probs, temps, topps, outTok);
    }
}

// Round 13
// 439.325 us; speedup vs baseline: 1.1118x; 1.1118x over previous
//
#include <hip/hip_runtime.h>
#include <stdint.h>

#define N_TOK 256
#define D_MODEL 1024
#define VOCAB 128000
#define NV_ELEMS (256LL * 128000LL)
#define LIST_CAP 24576      // old fallback sampler (in-LDS, has overflow fallback)
#define GLIST_CAP 131072    // > VOCAB: per-row compaction can NEVER drop -> deterministic

typedef unsigned long long u64;
typedef uint32_t u32;
typedef __attribute__((ext_vector_type(8))) short bfrag;   // 8 bf16 (4 VGPR)
typedef __attribute__((ext_vector_type(4))) float facc;    // 4 f32

// ===================== helpers =====================
__device__ __forceinline__ uint32_t bf16_rne_bits(float x) {
    uint32_t u = __float_as_uint(x);
    return (u + 0x7fffu + ((u >> 16) & 1u)) >> 16;
}

__device__ __forceinline__ uint32_t rotl32(uint32_t x, int d) {
    return (x << d) | (x >> (32 - d));
}

// monotone key for f32 bits (order-preserving over all finite floats)
__device__ __forceinline__ u32 mono32(u32 b) {
    return (b & 0x80000000u) ? ~b : (b | 0x80000000u);
}
__device__ __forceinline__ float unmono32(u32 k) {
    u32 b = (k & 0x80000000u) ? (k & 0x7FFFFFFFu) : ~k;
    return __uint_as_float(b);
}

// fixed-point mass: rv * 2^30 (u64). order-independent integer sums.
__device__ __forceinline__ u64 fixmass(float rv) {
    return (u64)(rv * 1073741824.0f);
}

// JAX threefry2x32, key=(0,42) (KAT-verified core)
__device__ __forceinline__ uint2 tf_0_42(uint32_t c0, uint32_t c1) {
    const uint32_t ks0 = 0u, ks1 = 42u, ks2 = 0x1BD11BDAu ^ 42u;
    uint32_t x0 = c0 + ks0, x1 = c1 + ks1;
#define R4(a,b,c,d) \
    x0 += x1; x1 = rotl32(x1,a); x1 ^= x0; \
    x0 += x1; x1 = rotl32(x1,b); x1 ^= x0; \
    x0 += x1; x1 = rotl32(x1,c); x1 ^= x0; \
    x0 += x1; x1 = rotl32(x1,d); x1 ^= x0;
    R4(13,15,26,6)   x0 += ks1; x1 += ks2 + 1u;
    R4(17,29,16,24)  x0 += ks2; x1 += ks0 + 2u;
    R4(13,15,26,6)   x0 += ks0; x1 += ks1 + 3u;
    R4(17,29,16,24)  x0 += ks1; x1 += ks2 + 4u;
    R4(13,15,26,6)   x0 += ks2; x1 += ks0 + 5u;
#undef R4
    return make_uint2(x0, x1);
}

// partitionable threefry bits: counter=(0,j), out = x^y (verified r3)
__device__ __forceinline__ uint32_t jax_bits(uint32_t j) {
    uint2 r = tf_0_42(0u, j);
    return r.x ^ r.y;
}

__device__ __forceinline__ float jax_gumbel(uint32_t bits) {
    const float TINY = 1.17549435e-38f;
    float u = __uint_as_float((bits >> 9) | 0x3f800000u) - 1.0f;
    u = u + TINY;
    u = fmaxf(TINY, u);
    return -__logf(-__logf(u));
}

__device__ __forceinline__ float rv_of(float l, float rinv) {
    return __expf(l * rinv);
}

// async 16B global->LDS (dest = lbase + lane*16)
__device__ __forceinline__ void async_copy16(const void* g, void* lbase, int lane) {
#if defined(__has_builtin) && __has_builtin(__builtin_amdgcn_global_load_lds)
    __builtin_amdgcn_global_load_lds((const uint32_t*)g, (uint32_t*)lbase, 16, 0, 0);
#else
    *(bfrag*)((char*)lbase + lane * 16) = *(const bfrag*)g;
#endif
}

// descending-bucket scan, one wave (lanes 0..63), exact u64 arithmetic
__device__ __forceinline__ void scan_desc_u64(const u64* h, int nb, u64 carry, u64 P,
                                              int* outCb, u64* outSa) {
    int lane = (int)threadIdx.x & 63;
    int chunk = nb >> 6;
    int top = nb - 1 - lane * chunk;
    u64 ls = 0ull;
    for (int j = 0; j < chunk; ++j) ls += h[top - j];
    u64 incl = ls;
    for (int o = 1; o < 64; o <<= 1) {
        u64 v = __shfl_up(incl, o, 64);
        if (lane >= o) incl += v;
    }
    u64 s0 = carry + incl - ls;
    unsigned long long mask = __ballot(s0 + ls > P);
    if (mask == 0ull) {
        if (lane == 0) { *outCb = 0; *outSa = carry; }   // cannot happen (P < total)
    } else {
        int cstar = (int)__builtin_ctzll(mask);
        if (lane == cstar) {
            u64 sa = s0; int cb = 0;
            for (int j = 0; j < chunk; ++j) {
                int b = top - j;
                if (sa + h[b] > P) { cb = b; break; }
                sa += h[b];
            }
            *outCb = cb; *outSa = sa;
        }
    }
}

// ============ A pre-convert (gather + split-bf16 + swizzled image, BK=32) ====
__global__ __launch_bounds__(256) void prep_a(
        const float* __restrict__ hidden, const int* __restrict__ idx,
        ushort* __restrict__ wsA) {
    const int m = blockIdx.x;
    const int t = threadIdx.x;
    const float* src = hidden + (long long)idx[m] * D_MODEL;
    const uint32_t swz = (uint32_t)((m & 7) << 4);
    for (int j = 0; j < 4; ++j) {
        int k = t * 4 + j;
        float x = src[k];
        uint32_t hb = bf16_rne_bits(x);
        float hf = __uint_as_float(hb << 16);
        uint32_t lb = bf16_rne_bits(x - hf);
        int kt = k >> 5, kk = k & 31, g = kk >> 3, e = kk & 7;
        char* img = (char*)wsA + (size_t)kt * 32768;
        uint32_t base = (uint32_t)(m * 128 + g * 32);
        *(ushort*)(img + ((base + 0) ^ swz) + e * 2) = (ushort)hb;
        *(ushort*)(img + ((base + 16) ^ swz) + e * 2) = (ushort)lb;
    }
}

// ===== split-bf16 MFMA GEMM — EXACT r5/r10 measured-best (BM=256,BN=64,BK=32,
// 4 waves, 40 KB LDS, stage->barrier->MFMA; TLP from 4 blocks/CU does the
// latency hiding — every prefetch variant (r7/r8/r9/r11) lost ~115 µs) =====
__global__ __launch_bounds__(256) void gemm_mfma(
        const ushort* __restrict__ wsA, const float* __restrict__ emb,
        float* __restrict__ logits) {
    __shared__ __align__(16) ushort Aimg[16384];  // 32 KB swizzled A K-tile
    __shared__ __align__(16) ushort Bimg[4096];   // 8 KB swizzled B K-tile
    const int tid = (int)threadIdx.x;
    const int w = tid >> 6, l = tid & 63;
    const int lr = l & 15, lg = l >> 4;
    const int v0 = blockIdx.x * 64;
    char* Ab = (char*)Aimg;
    char* Bb = (char*)Bimg;

    facc acc[4][4] = {};

    for (int kt = 0; kt < 32; ++kt) {
        __syncthreads();
        // stage A: async linear copy of pre-swizzled 32 KB image
        const char* asrc = (const char*)wsA + (size_t)kt * 32768;
#pragma unroll
        for (int i = 0; i < 8; ++i) {
            int off = w * 8192 + i * 1024;
            async_copy16(asrc + off + l * 16, Ab + off, l);
        }
        // stage B: 64 rows x 32 k, f32 -> bf16 hi/lo, swizzled b128 writes
        {
            int rb = tid >> 2, g = tid & 3;
            const float* bs = emb + (size_t)(v0 + rb) * D_MODEL + kt * 32 + g * 8;
            float4 x0 = *(const float4*)bs;
            float4 x1 = *(const float4*)(bs + 4);
            float xs[8] = {x0.x, x0.y, x0.z, x0.w, x1.x, x1.y, x1.z, x1.w};
            bfrag h, lo;
#pragma unroll
            for (int e = 0; e < 8; ++e) {
                uint32_t hb = bf16_rne_bits(xs[e]);
                float hf = __uint_as_float(hb << 16);
                uint32_t lb = bf16_rne_bits(xs[e] - hf);
                h[e] = (short)hb; lo[e] = (short)lb;
            }
            uint32_t swz = (uint32_t)((rb & 7) << 4);
            uint32_t base = (uint32_t)(rb * 128 + g * 32);
            *(bfrag*)(Bb + ((base + 0) ^ swz)) = h;
            *(bfrag*)(Bb + ((base + 16) ^ swz)) = lo;
        }
        __syncthreads();
        // MFMA: k-group per lane = lg (K=32 per kt)
        bfrag bh[4], bl[4];
#pragma unroll
        for (int nj = 0; nj < 4; ++nj) {
            int rb = nj * 16 + lr;
            uint32_t swz = (uint32_t)((rb & 7) << 4);
            uint32_t base = (uint32_t)(rb * 128 + lg * 32);
            bh[nj] = *(const bfrag*)(Bb + ((base + 0) ^ swz));
            bl[nj] = *(const bfrag*)(Bb + ((base + 16) ^ swz));
        }
#pragma unroll
        for (int mi = 0; mi < 4; ++mi) {
            int r = w * 64 + mi * 16 + lr;
            uint32_t swz = (uint32_t)((r & 7) << 4);
            uint32_t base = (uint32_t)(r * 128 + lg * 32);
            bfrag ah = *(const bfrag*)(Ab + ((base + 0) ^ swz));
            bfrag al = *(const bfrag*)(Ab + ((base + 16) ^ swz));
#pragma unroll
            for (int nj = 0; nj < 4; ++nj) {
                acc[mi][nj] = __builtin_amdgcn_mfma_f32_16x16x32_bf16(ah, bh[nj], acc[mi][nj], 0, 0, 0);
                acc[mi][nj] = __builtin_amdgcn_mfma_f32_16x16x32_bf16(ah, bl[nj], acc[mi][nj], 0, 0, 0);
                acc[mi][nj] = __builtin_amdgcn_mfma_f32_16x16x32_bf16(al, bh[nj], acc[mi][nj], 0, 0, 0);
            }
        }
    }
    // C write: row = w*64 + mi*16 + lg*4 + reg, col = v0 + nj*16 + lr
#pragma unroll
    for (int mi = 0; mi < 4; ++mi) {
        int mbase = w * 64 + mi * 16 + lg * 4;
#pragma unroll
        for (int nj = 0; nj < 4; ++nj) {
            int v = v0 + nj * 16 + lr;
#pragma unroll
            for (int reg = 0; reg < 4; ++reg)
                logits[(size_t)(mbase + reg) * VOCAB + v] = acc[mi][nj][reg];
        }
    }
}

// ===================== f32 GEMM fallback (ws too small) =====================
__global__ __launch_bounds__(256) void gemm_kernel(
        const float* __restrict__ hidden, const int* __restrict__ idx,
        const float* __restrict__ emb, float* __restrict__ logits) {
    __shared__ float As[16][64];
    __shared__ float Bs[16][64];
    const int n0 = blockIdx.x * 64, v0 = blockIdx.y * 64;
    const int tid = threadIdx.x;
    const int tx = tid & 15, ty = tid >> 4;
    const int lr = tid >> 2, lk = (tid & 3) * 4;
    float acc[4][4] = {};
    const long long aRow = (long long)idx[n0 + lr] * D_MODEL + lk;
    const long long bRow = (long long)(v0 + lr) * D_MODEL + lk;
    for (int k0 = 0; k0 < D_MODEL; k0 += 16) {
        float4 av = *(const float4*)(hidden + aRow + k0);
        float4 bv = *(const float4*)(emb + bRow + k0);
        __syncthreads();
        As[lk + 0][lr] = av.x; As[lk + 1][lr] = av.y; As[lk + 2][lr] = av.z; As[lk + 3][lr] = av.w;
        Bs[lk + 0][lr] = bv.x; Bs[lk + 1][lr] = bv.y; Bs[lk + 2][lr] = bv.z; Bs[lk + 3][lr] = bv.w;
        __syncthreads();
#pragma unroll
        for (int kk = 0; kk < 16; ++kk) {
            float4 a = *(const float4*)&As[kk][ty * 4];
            float4 b = *(const float4*)&Bs[kk][tx * 4];
            float aa[4] = {a.x, a.y, a.z, a.w};
            float bb[4] = {b.x, b.y, b.z, b.w};
#pragma unroll
            for (int i = 0; i < 4; ++i)
#pragma unroll
                for (int j = 0; j < 4; ++j)
                    acc[i][j] += aa[i] * bb[j];
        }
    }
#pragma unroll
    for (int i = 0; i < 4; ++i) {
        float4 o = make_float4(acc[i][0], acc[i][1], acc[i][2], acc[i][3]);
        *(float4*)(logits + (long long)(n0 + ty * 4 + i) * VOCAB + (v0 + tx * 4)) = o;
    }
}

// ===================== sampler pipeline (6 kernels) =====================
// K1: per-row-quarter L1 histogram -> NON-ATOMIC per-block partial slice
//     (no memset needed; slices live in the 'list' region, time-disjoint)
__global__ __launch_bounds__(512) void hist1_kernel(
        const float* __restrict__ probs, const float* __restrict__ temps,
        u64* __restrict__ hpart) {
    const int row = blockIdx.y, hb = blockIdx.x, tid = (int)threadIdx.x;
    __shared__ u64 h[4096];
    for (int i = tid; i < 4096; i += 512) h[i] = 0ull;
    __syncthreads();
    const float rinv = 1.0f / temps[row];
    const float4* R4 = (const float4*)(probs + (size_t)row * VOCAB);
    const int base4 = hb * 8000;
    for (int i = 0; i < 16; ++i) {
        int j = tid + i * 512;
        if (j < 8000) {
            float4 x = R4[base4 + j];
            float xs[4] = {x.x, x.y, x.z, x.w};
#pragma unroll
            for (int c = 0; c < 4; ++c) {
                u32 key = mono32(__float_as_uint(xs[c]));
                atomicAdd(&h[key >> 20], fixmass(rv_of(xs[c], rinv)));
            }
        }
    }
    __syncthreads();
    u64* gh = hpart + ((size_t)row * 4 + hb) * 4096;
    for (int i = tid; i < 4096; i += 512) gh[i] = h[i];   // full overwrite
}

// K2: sum 4 partial slices in LDS, exact u64 descending scan; also zeroes
//     listCnt/argmax for the downstream kernels (replaces memsets)
__global__ __launch_bounds__(64) void scan1_kernel(
        const u64* __restrict__ hpart, const float* __restrict__ topps,
        u64* __restrict__ rsP, u64* __restrict__ rsCarry, u32* __restrict__ rsCb,
        u32* __restrict__ listCnt, u64* __restrict__ argmax) {
    const int row = blockIdx.x, lane = (int)threadIdx.x;
    __shared__ u64 sh[4096];
    const u64* hp = hpart + (size_t)row * 4 * 4096;
    u64 S = 0ull;
    for (int j = lane; j < 4096; j += 64) {
        u64 v = hp[j] + hp[4096 + j] + hp[8192 + j] + hp[12288 + j];
        sh[j] = v;
        S += v;
    }
    __syncthreads();
    for (int o = 32; o >= 1; o >>= 1) S += __shfl_xor(S, o, 64);
    const u64 P = (u64)((double)topps[row] * (double)S);
    __shared__ int sCb; __shared__ u64 sSa;
    scan_desc_u64(sh, 4096, 0ull, P, &sCb, &sSa);
    __syncthreads();
    if (lane == 0) {
        rsP[row] = P; rsCarry[row] = sSa; rsCb[row] = (u32)sCb;
        listCnt[row] = 0u; argmax[row] = 0ull;
    }
}

// K3: compact (key, idx) of cut L1 bucket -> per-row list (LDS-staged, G12).
// GLIST_CAP > VOCAB: no entry can ever be dropped -> deterministic across
// replays (r12 failure root cause: cap-overflow drops were arrival-ordered).
__global__ __launch_bounds__(512) void compact_kernel(
        const float* __restrict__ probs, const u32* __restrict__ rsCb,
        u64* __restrict__ list, u32* __restrict__ listCnt) {
    const int row = blockIdx.y, hb = blockIdx.x, tid = (int)threadIdx.x;
    __shared__ u64 buf[4096];
    __shared__ u32 lcnt, gbase;
    const u32 cb1 = rsCb[row];
    const float4* R4 = (const float4*)(probs + (size_t)row * VOCAB);
    u64* lst = list + (size_t)row * GLIST_CAP;
    const int base4 = hb * 8000;
    if (tid == 0) lcnt = 0u;
    __syncthreads();
    for (int pair = 0; pair < 8; ++pair) {
#pragma unroll
        for (int s = 0; s < 2; ++s) {
            int j = tid + (pair * 2 + s) * 512;
            if (j < 8000) {
                float4 x = R4[base4 + j];
                float xs[4] = {x.x, x.y, x.z, x.w};
#pragma unroll
                for (int c = 0; c < 4; ++c) {
                    u32 key = mono32(__float_as_uint(xs[c]));
                    if ((key >> 20) == cb1) {
                        u32 pos = atomicAdd(&lcnt, 1u);
                        buf[pos] = ((u64)key << 32) | (u32)((base4 + j) * 4 + c);
                    }
                }
            }
        }
        __syncthreads();
        u32 n = lcnt;
        if (n) {
            if (tid == 0) gbase = atomicAdd(&listCnt[row], n);
            __syncthreads();
            u32 gb = gbase;
            for (u32 i2 = tid; i2 < n; i2 += 512) {
                u32 gpos = gb + i2;
                if (gpos < GLIST_CAP) lst[gpos] = buf[i2];
            }
        }
        __syncthreads();
        if (tid == 0) lcnt = 0u;
        __syncthreads();
    }
}

// K4: in-LDS L2/L3 refinement over the compacted list -> exact ts, mt, Sp, ties
__global__ __launch_bounds__(1024) void resolve_kernel(
        const u64* __restrict__ list, const u32* __restrict__ listCnt,
        const u64* __restrict__ rsP, const u64* __restrict__ rsCarry,
        const u32* __restrict__ rsCb, const float* __restrict__ temps,
        u32* __restrict__ scTs, u32* __restrict__ scTieN,
        float* __restrict__ scInvSp, u32* __restrict__ tieKept) {
    const int row = blockIdx.x, tid = (int)threadIdx.x;
    __shared__ u64 h2[1024];
    __shared__ u32 c3[1024];
    __shared__ int sCb; __shared__ u64 sSa;
    __shared__ u32 sTc;
    __shared__ u32 tlist[1024];
    const u32 cnt = min(listCnt[row], (u32)GLIST_CAP);
    const u64 P = rsP[row];
    const float rinv = 1.0f / temps[row];
    const u64* lst = list + (size_t)row * GLIST_CAP;

    h2[tid] = 0ull;
    __syncthreads();
    for (u32 j = tid; j < cnt; j += 1024) {
        u32 key = (u32)(lst[j] >> 32);
        atomicAdd(&h2[(key >> 10) & 1023u], fixmass(rv_of(unmono32(key), rinv)));
    }
    __syncthreads();
    if (tid < 64) scan_desc_u64(h2, 1024, rsCarry[row], P, &sCb, &sSa);
    __syncthreads();
    const u32 cb2 = (u32)sCb; const u64 carry2 = sSa;
    __syncthreads();

    h2[tid] = 0ull; c3[tid] = 0u;
    __syncthreads();
    for (u32 j = tid; j < cnt; j += 1024) {
        u32 key = (u32)(lst[j] >> 32);
        if (((key >> 10) & 1023u) == cb2) {
            atomicAdd(&h2[key & 1023u], fixmass(rv_of(unmono32(key), rinv)));
            atomicAdd(&c3[key & 1023u], 1u);
        }
    }
    __syncthreads();
    if (tid < 64) scan_desc_u64(h2, 1024, carry2, P, &sCb, &sSa);
    __syncthreads();
    const int cb3 = sCb; const u64 sa3 = sSa;
    const u32 ts = (rsCb[row] << 20) | (cb2 << 10) | (u32)cb3;
    u32 cntb = c3[cb3]; if (cntb == 0u) cntb = 1u;
    const u64 tfq = fixmass(rv_of(unmono32(ts), rinv));
    const u64 rem = P - sa3;
    u32 mt;
    if (tfq == 0ull) mt = cntb;
    else {
        u64 q = rem / tfq;
        mt = (q >= (u64)(cntb - 1)) ? cntb : ((u32)q + 1u);
    }
    const u64 Spq = sa3 + (u64)mt * tfq;

    if (tid == 0) sTc = 0u;
    __syncthreads();
    for (u32 j = tid; j < cnt; j += 1024) {
        if ((u32)(lst[j] >> 32) == ts) {
            u32 pos = atomicAdd(&sTc, 1u);
            if (pos < 1024u) tlist[pos] = (u32)lst[j];
        }
    }
    __syncthreads();
    const u32 tn = min(sTc, 1024u);
    if ((u32)tid < tn) {
        u32 my = tlist[tid];
        u32 rank = 0;
        for (u32 j2 = 0; j2 < tn; ++j2) rank += (tlist[j2] < my) ? 1u : 0u;
        if (rank < mt) tieKept[(size_t)row * 1024 + rank] = my;
    }
    if (tid == 0) {
        scTs[row] = ts;
        scTieN[row] = min(mt, tn);
        scInvSp[row] = (float)(1073741824.0 / (double)Spq);
    }
}

// K5: write probs_f + gumbel-argmax (exp/gumbel only for kept elems)
__global__ __launch_bounds__(512) void final2_kernel(
        float* __restrict__ probs, const float* __restrict__ temps,
        const u32* __restrict__ scTs, const u32* __restrict__ scTieN,
        const float* __restrict__ scInvSp, const u32* __restrict__ tieKept,
        u64* __restrict__ argmax) {
    const int row = blockIdx.y, hb = blockIdx.x, tid = (int)threadIdx.x;
    __shared__ u32 tl[1024];
    __shared__ u64 wbest[8];
    const u32 ts = scTs[row], tieN = scTieN[row];
    const float invSp = scInvSp[row];
    const float rinv = 1.0f / temps[row];
    for (u32 i = tid; i < tieN; i += 512) tl[i] = tieKept[(size_t)row * 1024 + i];
    __syncthreads();
    float4* R4 = (float4*)(probs + (size_t)row * VOCAB);
    const u32 rowBase = (u32)row * (u32)VOCAB;
    const int base4 = hb * 8000;
    u64 best = 0ull;
    for (int i = 0; i < 16; ++i) {
        int j = tid + i * 512;
        if (j < 8000) {
            float4 x = R4[base4 + j];
            float xs[4] = {x.x, x.y, x.z, x.w};
            float4 out;
            float* op = (float*)&out;
#pragma unroll
            for (int c = 0; c < 4; ++c) {
                u32 key = mono32(__float_as_uint(xs[c]));
                u32 v = (u32)((base4 + j) * 4 + c);
                bool kept = key > ts;
                if (key == ts) {
                    kept = false;
                    for (u32 q2 = 0; q2 < tieN; ++q2)
                        if (tl[q2] == v) { kept = true; break; }
                }
                if (kept) {
                    float pf = rv_of(xs[c], rinv) * invSp;
                    op[c] = pf;
                    float g = jax_gumbel(jax_bits(rowBase + v));
                    float val = __logf(pf + 1e-20f) + g;
                    u64 pk = ((u64)mono32(__float_as_uint(val)) << 32) | (u32)(~v);
                    if (pk > best) best = pk;
                } else {
                    op[c] = 0.0f;
                }
            }
            R4[base4 + j] = out;
        }
    }
    for (int o = 32; o >= 1; o >>= 1) {
        u64 ob = __shfl_xor(best, o, 64);
        if (ob > best) best = ob;
    }
    if ((tid & 63) == 0) wbest[tid >> 6] = best;
    __syncthreads();
    if (tid == 0) {
        u64 b = wbest[0];
        for (int w2 = 1; w2 < 8; ++w2) if (wbest[w2] > b) b = wbest[w2];
        atomicMax(&argmax[row], b);
    }
}

// K6: token write
__global__ void token_kernel(const u64* __restrict__ argmax, float* __restrict__ outTok) {
    int n = (int)threadIdx.x;
    if (n < N_TOK) outTok[n] = (float)(~(u32)argmax[n]);
}

// ============== OLD fused per-row sampler (r5 verified; ws fallback) ========
__device__ __forceinline__ void scan_desc_wave(const float* h, int nb, float carry,
                                               float P, int* outCb, float* outSa) {
    int lane = (int)threadIdx.x & 63;
    int chunk = nb >> 6;
    int top = nb - 1 - lane * chunk;
    float ls = 0.0f;
    for (int j = 0; j < chunk; ++j) ls += h[top - j];
    float incl = ls;
    for (int o = 1; o < 64; o <<= 1) {
        float v = __shfl_up(incl, o, 64);
        if (lane >= o) incl += v;
    }
    float s0 = carry + incl - ls;
    unsigned long long mask = __ballot(s0 + ls > P);
    if (mask == 0ull) {
        if (lane == 63) { *outCb = 0; *outSa = carry + incl - h[0]; }
    } else {
        int cstar = (int)__builtin_ctzll(mask);
        if (lane == cstar) {
            float sa = s0; int cb = 0;
            for (int j = 0; j < chunk; ++j) {
                int b = top - j;
                if (sa + h[b] > P) { cb = b; break; }
                sa += h[b];
            }
            *outCb = cb; *outSa = sa;
        }
    }
}

__global__ __launch_bounds__(1024) void sample_kernel(
        float* __restrict__ probs, const float* __restrict__ temps,
        const float* __restrict__ topps, float* __restrict__ outTok) {
    const int row = blockIdx.x;
    const int tid = (int)threadIdx.x;
    float* L = probs + (long long)row * VOCAB;
    const float4* L4 = (const float4*)L;
    float4* L4w = (float4*)L;

    __shared__ float waveH[16][2048];
    __shared__ float hsum[2048];
    __shared__ uint32_t hcnt[1024];
    __shared__ float wred[16];
    __shared__ float aVal[16];
    __shared__ int aIdx[16];
    __shared__ uint32_t tieList[256];
    __shared__ int sCb;
    __shared__ float sSa;
    __shared__ float sP, sCarry1, sCarry2, sSp, sInvSp;
    __shared__ uint32_t sPref1, sCb2, sTsKey, sMt, sTieN, sCnt;
    uint32_t* keys = (uint32_t*)&waveH[4][0];

    const float t = temps[row];
    const float p = topps[row];
    const float rinv = 1.0f / t;

    for (int i = tid; i < 16 * 2048; i += 1024) ((float*)waveH)[i] = 0.0f;
    __syncthreads();
    {
        float* myH = waveH[tid >> 6];
#pragma unroll 2
        for (int i = 0; i < 31; ++i) {
            float4 x = L4[tid + i * 1024];
            float r0 = rv_of(x.x, rinv), r1 = rv_of(x.y, rinv);
            float r2 = rv_of(x.z, rinv), r3 = rv_of(x.w, rinv);
            atomicAdd(&myH[__float_as_uint(r0) >> 20], r0);
            atomicAdd(&myH[__float_as_uint(r1) >> 20], r1);
            atomicAdd(&myH[__float_as_uint(r2) >> 20], r2);
            atomicAdd(&myH[__float_as_uint(r3) >> 20], r3);
        }
        if (tid < 256) {
            float4 x = L4[31744 + tid];
            float r0 = rv_of(x.x, rinv), r1 = rv_of(x.y, rinv);
            float r2 = rv_of(x.z, rinv), r3 = rv_of(x.w, rinv);
            atomicAdd(&myH[__float_as_uint(r0) >> 20], r0);
            atomicAdd(&myH[__float_as_uint(r1) >> 20], r1);
            atomicAdd(&myH[__float_as_uint(r2) >> 20], r2);
            atomicAdd(&myH[__float_as_uint(r3) >> 20], r3);
        }
    }
    __syncthreads();
    {
        float a0 = 0.0f, a1 = 0.0f;
#pragma unroll
        for (int w2 = 0; w2 < 16; ++w2) { a0 += waveH[w2][tid]; a1 += waveH[w2][tid + 1024]; }
        hsum[tid] = a0; hsum[tid + 1024] = a1;
        float s = a0 + a1;
        for (int o = 32; o >= 1; o >>= 1) s += __shfl_xor(s, o, 64);
        if ((tid & 63) == 0) wred[tid >> 6] = s;
    }
    __syncthreads();
    if (tid == 0) {
        float tot = 0.0f;
        for (int w2 = 0; w2 < 16; ++w2) tot += wred[w2];
        sP = p * tot;
    }
    __syncthreads();
    if (tid < 64) scan_desc_wave(hsum, 2048, 0.0f, sP, &sCb, &sSa);
    __syncthreads();
    if (tid == 0) { sPref1 = (uint32_t)sCb; sCarry1 = sSa; sCnt = 0u; }
    __syncthreads();

    const uint32_t pref1 = sPref1;
    const float P = sP;
#pragma unroll 2
    for (int i = 0; i < 31; ++i) {
        float4 x = L4[tid + i * 1024];
        float rr[4] = {rv_of(x.x, rinv), rv_of(x.y, rinv), rv_of(x.z, rinv), rv_of(x.w, rinv)};
#pragma unroll
        for (int c = 0; c < 4; ++c) {
            uint32_t key = __float_as_uint(rr[c]);
            if ((key >> 20) == pref1) {
                uint32_t pos = atomicAdd(&sCnt, 1u);
                if (pos < LIST_CAP) keys[pos] = key;
            }
        }
    }
    if (tid < 256) {
        float4 x = L4[31744 + tid];
        float rr[4] = {rv_of(x.x, rinv), rv_of(x.y, rinv), rv_of(x.z, rinv), rv_of(x.w, rinv)};
#pragma unroll
        for (int c = 0; c < 4; ++c) {
            uint32_t key = __float_as_uint(rr[c]);
            if ((key >> 20) == pref1) {
                uint32_t pos = atomicAdd(&sCnt, 1u);
                if (pos < LIST_CAP) keys[pos] = key;
            }
        }
    }
    __syncthreads();
    const uint32_t K = sCnt;
    const bool inLds = (K <= LIST_CAP);

    if (tid < 1024) hsum[tid] = 0.0f;
    __syncthreads();
    if (inLds) {
        for (uint32_t j = tid; j < K; j += 1024) {
            uint32_t key = keys[j];
            atomicAdd(&hsum[(key >> 10) & 1023u], __uint_as_float(key));
        }
    } else {
        for (int i = 0; i < 125; ++i) {
            int v = tid + i * 1024;
            float rv = rv_of(L[v], rinv);
            uint32_t key = __float_as_uint(rv);
            if ((key >> 20) == pref1) atomicAdd(&hsum[(key >> 10) & 1023u], rv);
        }
    }
    __syncthreads();
    if (tid < 64) scan_desc_wave(hsum, 1024, sCarry1, P, &sCb, &sSa);
    __syncthreads();
    if (tid == 0) { sCb2 = (uint32_t)sCb; sCarry2 = sSa; }
    __syncthreads();

    const uint32_t cb2 = sCb2;
    if (tid < 1024) { hsum[tid] = 0.0f; hcnt[tid] = 0u; }
    __syncthreads();
    if (inLds) {
        for (uint32_t j = tid; j < K; j += 1024) {
            uint32_t key = keys[j];
            if (((key >> 10) & 1023u) == cb2) {
                atomicAdd(&hsum[key & 1023u], __uint_as_float(key));
                atomicAdd(&hcnt[key & 1023u], 1u);
            }
        }
    } else {
        const uint32_t pref2full = (pref1 << 10) | cb2;
        for (int i = 0; i < 125; ++i) {
            int v = tid + i * 1024;
            float rv = rv_of(L[v], rinv);
            uint32_t key = __float_as_uint(rv);
            if ((key >> 10) == pref2full) {
                atomicAdd(&hsum[key & 1023u], rv);
                atomicAdd(&hcnt[key & 1023u], 1u);
            }
        }
    }
    __syncthreads();
    if (tid < 64) scan_desc_wave(hsum, 1024, sCarry2, P, &sCb, &sSa);
    __syncthreads();
    if (tid == 0) {
        int cb3 = sCb; float sa3 = sSa;
        uint32_t ts = (pref1 << 20) | (cb2 << 10) | (uint32_t)cb3;
        uint32_t cnt = hcnt[cb3]; if (cnt == 0u) cnt = 1u;
        float tf = __uint_as_float(ts);
        uint32_t mt;
        float rem = P - sa3; if (rem < 0.0f) rem = 0.0f;
        if (!(tf > 0.0f)) mt = cnt;
        else {
            float q = floorf(rem / tf);
            mt = (q >= (float)(cnt - 1)) ? cnt : ((uint32_t)q + 1u);
        }
        sTsKey = ts; sMt = mt;
        sSp = sa3 + (float)mt * tf;
        sInvSp = 1.0f / sSp;
        sTieN = 0u;
    }
    __syncthreads();

    const uint32_t ts = sTsKey, mt = sMt;
    const float invSp = sInvSp;
    float bestV = -INFINITY;
    int bestI = 0x7FFFFFFF;
    const uint32_t rowBase = (uint32_t)row * (uint32_t)VOCAB;
    for (int i = 0; i < 32; ++i) {
        int f4i = (i < 31) ? (tid + i * 1024) : (31744 + tid);
        if (i == 31 && tid >= 256) break;
        float4 x = L4[f4i];
        float rr[4] = {rv_of(x.x, rinv), rv_of(x.y, rinv), rv_of(x.z, rinv), rv_of(x.w, rinv)};
        float4 out;
        float* op = (float*)&out;
#pragma unroll
        for (int c = 0; c < 4; ++c) {
            uint32_t key = __float_as_uint(rr[c]);
            int v = f4i * 4 + c;
            if (key > ts) {
                float pf = rr[c] * invSp;
                op[c] = pf;
                float g = jax_gumbel(jax_bits(rowBase + (uint32_t)v));
                float val = __logf(pf + 1e-20f) + g;
                if (val > bestV || (val == bestV && v < bestI)) { bestV = val; bestI = v; }
            } else if (key == ts) {
                op[c] = 0.0f;
                uint32_t pos = atomicAdd(&sTieN, 1u);
                if (pos < 256u) tieList[pos] = (uint32_t)v;
            } else {
                op[c] = 0.0f;
            }
        }
        L4w[f4i] = out;
    }
    __syncthreads();
    {
        const uint32_t tn = min(sTieN, 256u);
        if ((uint32_t)tid < tn) {
            uint32_t v = tieList[tid];
            uint32_t rank = 0;
            for (uint32_t j = 0; j < tn; ++j) rank += (tieList[j] < v) ? 1u : 0u;
            if (rank < mt) {
                float pf = __uint_as_float(ts) * invSp;
                L[v] = pf;
                float g = jax_gumbel(jax_bits(rowBase + v));
                float val = __logf(pf + 1e-20f) + g;
                if (val > bestV || (val == bestV && (int)v < bestI)) { bestV = val; bestI = (int)v; }
            }
        }
    }
    for (int o = 32; o >= 1; o >>= 1) {
        float ov = __shfl_xor(bestV, o, 64);
        int oi = __shfl_xor(bestI, o, 64);
        if (ov > bestV || (ov == bestV && oi < bestI)) { bestV = ov; bestI = oi; }
    }
    if ((tid & 63) == 0) { aVal[tid >> 6] = bestV; aIdx[tid >> 6] = bestI; }
    __syncthreads();
    if (tid == 0) {
        float bv = aVal[0]; int bi = aIdx[0];
        for (int w2 = 1; w2 < 16; ++w2) {
            if (aVal[w2] > bv || (aVal[w2] == bv && aIdx[w2] < bi)) { bv = aVal[w2]; bi = aIdx[w2]; }
        }
        outTok[row] = (float)bi;
    }
}

// ===================== launch =====================
extern "C" void kernel_launch(void* const* d_in, const int* in_sizes, int n_in,
                              void* d_out, int out_size, void* d_ws, size_t ws_size,
                              hipStream_t stream) {
    const float* hidden = (const float*)d_in[0];
    const float* emb    = (const float*)d_in[1];
    const float* temps  = (const float*)d_in[2];
    const float* topps  = (const float*)d_in[3];
    const int*   idx    = (const int*)d_in[4];

    float* probs  = (float*)d_out;        // [N,V]: logits, then probs_f in place
    float* outTok = probs + NV_ELEMS;     // [N] tokens as f32

    char* ws = (char*)d_ws;
    const bool wsGemm = ws_size >= (size_t)(1u << 20);
    // list region: 256 rows x GLIST_CAP(131072) x 8 B = 256 MB at ws+2MB;
    // hist1 partial slices (32 MB) alias its start, time-disjoint.
    const bool wsBig  = ws_size >= (size_t)(280u << 20);

    if (wsGemm) {
        ushort* wsA = (ushort*)ws;        // 32 x 32 KB pre-swizzled A images
        prep_a<<<N_TOK, 256, 0, stream>>>(hidden, idx, wsA);
        gemm_mfma<<<VOCAB / 64, 256, 0, stream>>>(wsA, emb, probs);
    } else {
        gemm_kernel<<<dim3(4, 2000), 256, 0, stream>>>(hidden, idx, emb, probs);
    }

    if (wsBig) {
        u64* list      = (u64*)(ws + (2u << 20));    // 256 MB
        char* m        = ws + (2u << 20) + ((size_t)256u << 20);
        u32* listCnt   = (u32*)(m);                 // 1 KB
        u32* rsCb      = (u32*)(m + 1024);          // 1 KB
        u64* rsP       = (u64*)(m + 2048);          // 2 KB
        u64* rsCarry   = (u64*)(m + 4096);          // 2 KB
        u32* scTs      = (u32*)(m + 6144);          // 1 KB
        u32* scTieN    = (u32*)(m + 7168);          // 1 KB
        float* scInvSp = (float*)(m + 8192);        // 1 KB
        u64* argmax    = (u64*)(m + 9216);          // 2 KB
        u32* tieKept   = (u32*)(m + 16384);         // 1 MB

        hist1_kernel<<<dim3(4, N_TOK), 512, 0, stream>>>(probs, temps, list);
        scan1_kernel<<<N_TOK, 64, 0, stream>>>(list, topps, rsP, rsCarry, rsCb,
                                               listCnt, argmax);
        compact_kernel<<<dim3(4, N_TOK), 512, 0, stream>>>(probs, rsCb, list, listCnt);
        resolve_kernel<<<N_TOK, 1024, 0, stream>>>(list, listCnt, rsP, rsCarry, rsCb,
                                                   temps, scTs, scTieN, scInvSp, tieKept);
        final2_kernel<<<dim3(4, N_TOK), 512, 0, stream>>>(probs, temps, scTs, scTieN,
                                                          scInvSp, tieKept, argmax);
        token_kernel<<<1, 256, 0, stream>>>(argmax, outTok);
    } else {
        sample_kernel<<<N_TOK, 1024, 0, stream>>>(probs, temps, topps, outTok);
    }
}

// Round 14
// 433.962 us; speedup vs baseline: 1.1255x; 1.0124x over previous
//
#include <hip/hip_runtime.h>
#include <stdint.h>

#define N_TOK 256
#define D_MODEL 1024
#define VOCAB 128000
#define NV_ELEMS (256LL * 128000LL)
#define LIST_CAP 24576      // fallback sampler list cap
#define TIE_ALL 0xFFFFFFFFu // sentinel: every key==ts element is kept

typedef unsigned long long u64;
typedef uint32_t u32;
typedef __attribute__((ext_vector_type(8))) short bfrag;   // 8 bf16 (4 VGPR)
typedef __attribute__((ext_vector_type(4))) float facc;    // 4 f32

// ===================== helpers =====================
__device__ __forceinline__ uint32_t bf16_rne_bits(float x) {
    uint32_t u = __float_as_uint(x);
    return (u + 0x7fffu + ((u >> 16) & 1u)) >> 16;
}

__device__ __forceinline__ uint32_t rotl32(uint32_t x, int d) {
    return (x << d) | (x >> (32 - d));
}

// monotone key for f32 bits (order-preserving over all finite floats)
__device__ __forceinline__ u32 mono32(u32 b) {
    return (b & 0x80000000u) ? ~b : (b | 0x80000000u);
}
__device__ __forceinline__ float unmono32(u32 k) {
    u32 b = (k & 0x80000000u) ? (k & 0x7FFFFFFFu) : ~k;
    return __uint_as_float(b);
}

// fixed-point mass: rv * 2^30 (u64). order-independent integer sums.
__device__ __forceinline__ u64 fixmass(float rv) {
    return (u64)(rv * 1073741824.0f);
}

// JAX threefry2x32, key=(0,42) (KAT-verified core)
__device__ __forceinline__ uint2 tf_0_42(uint32_t c0, uint32_t c1) {
    const uint32_t ks0 = 0u, ks1 = 42u, ks2 = 0x1BD11BDAu ^ 42u;
    uint32_t x0 = c0 + ks0, x1 = c1 + ks1;
#define R4(a,b,c,d) \
    x0 += x1; x1 = rotl32(x1,a); x1 ^= x0; \
    x0 += x1; x1 = rotl32(x1,b); x1 ^= x0; \
    x0 += x1; x1 = rotl32(x1,c); x1 ^= x0; \
    x0 += x1; x1 = rotl32(x1,d); x1 ^= x0;
    R4(13,15,26,6)   x0 += ks1; x1 += ks2 + 1u;
    R4(17,29,16,24)  x0 += ks2; x1 += ks0 + 2u;
    R4(13,15,26,6)   x0 += ks0; x1 += ks1 + 3u;
    R4(17,29,16,24)  x0 += ks1; x1 += ks2 + 4u;
    R4(13,15,26,6)   x0 += ks2; x1 += ks0 + 5u;
#undef R4
    return make_uint2(x0, x1);
}

// partitionable threefry bits: counter=(0,j), out = x^y (verified r3)
__device__ __forceinline__ uint32_t jax_bits(uint32_t j) {
    uint2 r = tf_0_42(0u, j);
    return r.x ^ r.y;
}

__device__ __forceinline__ float jax_gumbel(uint32_t bits) {
    const float TINY = 1.17549435e-38f;
    float u = __uint_as_float((bits >> 9) | 0x3f800000u) - 1.0f;
    u = u + TINY;
    u = fmaxf(TINY, u);
    return -__logf(-__logf(u));
}

__device__ __forceinline__ float rv_of(float l, float rinv) {
    return __expf(l * rinv);
}

// async 16B global->LDS (dest = lbase + lane*16)
__device__ __forceinline__ void async_copy16(const void* g, void* lbase, int lane) {
#if defined(__has_builtin) && __has_builtin(__builtin_amdgcn_global_load_lds)
    __builtin_amdgcn_global_load_lds((const uint32_t*)g, (uint32_t*)lbase, 16, 0, 0);
#else
    *(bfrag*)((char*)lbase + lane * 16) = *(const bfrag*)g;
#endif
}

// descending-bucket scan, one wave (lanes 0..63), exact u64 arithmetic
__device__ __forceinline__ void scan_desc_u64(const u64* h, int nb, u64 carry, u64 P,
                                              int* outCb, u64* outSa) {
    int lane = (int)threadIdx.x & 63;
    int chunk = nb >> 6;
    int top = nb - 1 - lane * chunk;
    u64 ls = 0ull;
    for (int j = 0; j < chunk; ++j) ls += h[top - j];
    u64 incl = ls;
    for (int o = 1; o < 64; o <<= 1) {
        u64 v = __shfl_up(incl, o, 64);
        if (lane >= o) incl += v;
    }
    u64 s0 = carry + incl - ls;
    unsigned long long mask = __ballot(s0 + ls > P);
    if (mask == 0ull) {
        if (lane == 0) { *outCb = 0; *outSa = carry; }   // cannot happen (P < total)
    } else {
        int cstar = (int)__builtin_ctzll(mask);
        if (lane == cstar) {
            u64 sa = s0; int cb = 0;
            for (int j = 0; j < chunk; ++j) {
                int b = top - j;
                if (sa + h[b] > P) { cb = b; break; }
                sa += h[b];
            }
            *outCb = cb; *outSa = sa;
        }
    }
}

// ============ A pre-convert (gather + split-bf16 + swizzled image, BK=32) ====
__global__ __launch_bounds__(256) void prep_a(
        const float* __restrict__ hidden, const int* __restrict__ idx,
        ushort* __restrict__ wsA) {
    const int m = blockIdx.x;
    const int t = threadIdx.x;
    const float* src = hidden + (long long)idx[m] * D_MODEL;
    const uint32_t swz = (uint32_t)((m & 7) << 4);
    for (int j = 0; j < 4; ++j) {
        int k = t * 4 + j;
        float x = src[k];
        uint32_t hb = bf16_rne_bits(x);
        float hf = __uint_as_float(hb << 16);
        uint32_t lb = bf16_rne_bits(x - hf);
        int kt = k >> 5, kk = k & 31, g = kk >> 3, e = kk & 7;
        char* img = (char*)wsA + (size_t)kt * 32768;
        uint32_t base = (uint32_t)(m * 128 + g * 32);
        *(ushort*)(img + ((base + 0) ^ swz) + e * 2) = (ushort)hb;
        *(ushort*)(img + ((base + 16) ^ swz) + e * 2) = (ushort)lb;
    }
}

// ===== split-bf16 MFMA GEMM — r5/r10/r13 measured-best (BM=256,BN=64,BK=32,
// 4 waves, 40 KB LDS, stage->barrier->MFMA; 894 TF-equiv = the 2-barrier
// structural ceiling; all prefetch grafts (r7/r8/r9/r11) regressed) =====
__global__ __launch_bounds__(256) void gemm_mfma(
        const ushort* __restrict__ wsA, const float* __restrict__ emb,
        float* __restrict__ logits) {
    __shared__ __align__(16) ushort Aimg[16384];  // 32 KB swizzled A K-tile
    __shared__ __align__(16) ushort Bimg[4096];   // 8 KB swizzled B K-tile
    const int tid = (int)threadIdx.x;
    const int w = tid >> 6, l = tid & 63;
    const int lr = l & 15, lg = l >> 4;
    const int v0 = blockIdx.x * 64;
    char* Ab = (char*)Aimg;
    char* Bb = (char*)Bimg;

    facc acc[4][4] = {};

    for (int kt = 0; kt < 32; ++kt) {
        __syncthreads();
        // stage A: async linear copy of pre-swizzled 32 KB image
        const char* asrc = (const char*)wsA + (size_t)kt * 32768;
#pragma unroll
        for (int i = 0; i < 8; ++i) {
            int off = w * 8192 + i * 1024;
            async_copy16(asrc + off + l * 16, Ab + off, l);
        }
        // stage B: 64 rows x 32 k, f32 -> bf16 hi/lo, swizzled b128 writes
        {
            int rb = tid >> 2, g = tid & 3;
            const float* bs = emb + (size_t)(v0 + rb) * D_MODEL + kt * 32 + g * 8;
            float4 x0 = *(const float4*)bs;
            float4 x1 = *(const float4*)(bs + 4);
            float xs[8] = {x0.x, x0.y, x0.z, x0.w, x1.x, x1.y, x1.z, x1.w};
            bfrag h, lo;
#pragma unroll
            for (int e = 0; e < 8; ++e) {
                uint32_t hb = bf16_rne_bits(xs[e]);
                float hf = __uint_as_float(hb << 16);
                uint32_t lb = bf16_rne_bits(xs[e] - hf);
                h[e] = (short)hb; lo[e] = (short)lb;
            }
            uint32_t swz = (uint32_t)((rb & 7) << 4);
            uint32_t base = (uint32_t)(rb * 128 + g * 32);
            *(bfrag*)(Bb + ((base + 0) ^ swz)) = h;
            *(bfrag*)(Bb + ((base + 16) ^ swz)) = lo;
        }
        __syncthreads();
        // MFMA: k-group per lane = lg (K=32 per kt)
        bfrag bh[4], bl[4];
#pragma unroll
        for (int nj = 0; nj < 4; ++nj) {
            int rb = nj * 16 + lr;
            uint32_t swz = (uint32_t)((rb & 7) << 4);
            uint32_t base = (uint32_t)(rb * 128 + lg * 32);
            bh[nj] = *(const bfrag*)(Bb + ((base + 0) ^ swz));
            bl[nj] = *(const bfrag*)(Bb + ((base + 16) ^ swz));
        }
#pragma unroll
        for (int mi = 0; mi < 4; ++mi) {
            int r = w * 64 + mi * 16 + lr;
            uint32_t swz = (uint32_t)((r & 7) << 4);
            uint32_t base = (uint32_t)(r * 128 + lg * 32);
            bfrag ah = *(const bfrag*)(Ab + ((base + 0) ^ swz));
            bfrag al = *(const bfrag*)(Ab + ((base + 16) ^ swz));
#pragma unroll
            for (int nj = 0; nj < 4; ++nj) {
                acc[mi][nj] = __builtin_amdgcn_mfma_f32_16x16x32_bf16(ah, bh[nj], acc[mi][nj], 0, 0, 0);
                acc[mi][nj] = __builtin_amdgcn_mfma_f32_16x16x32_bf16(ah, bl[nj], acc[mi][nj], 0, 0, 0);
                acc[mi][nj] = __builtin_amdgcn_mfma_f32_16x16x32_bf16(al, bh[nj], acc[mi][nj], 0, 0, 0);
            }
        }
    }
    // C write: row = w*64 + mi*16 + lg*4 + reg, col = v0 + nj*16 + lr
#pragma unroll
    for (int mi = 0; mi < 4; ++mi) {
        int mbase = w * 64 + mi * 16 + lg * 4;
#pragma unroll
        for (int nj = 0; nj < 4; ++nj) {
            int v = v0 + nj * 16 + lr;
#pragma unroll
            for (int reg = 0; reg < 4; ++reg)
                logits[(size_t)(mbase + reg) * VOCAB + v] = acc[mi][nj][reg];
        }
    }
}

// ===================== f32 GEMM fallback (ws too small) =====================
__global__ __launch_bounds__(256) void gemm_kernel(
        const float* __restrict__ hidden, const int* __restrict__ idx,
        const float* __restrict__ emb, float* __restrict__ logits) {
    __shared__ float As[16][64];
    __shared__ float Bs[16][64];
    const int n0 = blockIdx.x * 64, v0 = blockIdx.y * 64;
    const int tid = threadIdx.x;
    const int tx = tid & 15, ty = tid >> 4;
    const int lr = tid >> 2, lk = (tid & 3) * 4;
    float acc[4][4] = {};
    const long long aRow = (long long)idx[n0 + lr] * D_MODEL + lk;
    const long long bRow = (long long)(v0 + lr) * D_MODEL + lk;
    for (int k0 = 0; k0 < D_MODEL; k0 += 16) {
        float4 av = *(const float4*)(hidden + aRow + k0);
        float4 bv = *(const float4*)(emb + bRow + k0);
        __syncthreads();
        As[lk + 0][lr] = av.x; As[lk + 1][lr] = av.y; As[lk + 2][lr] = av.z; As[lk + 3][lr] = av.w;
        Bs[lk + 0][lr] = bv.x; Bs[lk + 1][lr] = bv.y; Bs[lk + 2][lr] = bv.z; Bs[lk + 3][lr] = bv.w;
        __syncthreads();
#pragma unroll
        for (int kk = 0; kk < 16; ++kk) {
            float4 a = *(const float4*)&As[kk][ty * 4];
            float4 b = *(const float4*)&Bs[kk][tx * 4];
            float aa[4] = {a.x, a.y, a.z, a.w};
            float bb[4] = {b.x, b.y, b.z, b.w};
#pragma unroll
            for (int i = 0; i < 4; ++i)
#pragma unroll
                for (int j = 0; j < 4; ++j)
                    acc[i][j] += aa[i] * bb[j];
        }
    }
#pragma unroll
    for (int i = 0; i < 4; ++i) {
        float4 o = make_float4(acc[i][0], acc[i][1], acc[i][2], acc[i][3]);
        *(float4*)(logits + (long long)(n0 + ty * 4 + i) * VOCAB + (v0 + tx * 4)) = o;
    }
}

// ========== resolveC: fused per-row hist/scan L1->L2->L3 (+rare ties) ========
// One block per row; 3 full-row passes, but the row (500 KB) is L2-resident
// after pass A -> only pass A pays HBM. Same exact u64 bucket math as r13.
__global__ __launch_bounds__(1024) void resolveC_kernel(
        const float* __restrict__ probs, const float* __restrict__ temps,
        const float* __restrict__ topps,
        u32* __restrict__ scTs, u32* __restrict__ scTieN,
        float* __restrict__ scInvSp, u32* __restrict__ tieKept,
        u64* __restrict__ argmax) {
    const int row = blockIdx.x, tid = (int)threadIdx.x;
    __shared__ u64 h1[4096];       // L1 hist; [0..1023] reused for L2/L3
    __shared__ u32 c3[1024];
    __shared__ u32 tlist[1024];
    __shared__ u64 wredu[16];
    __shared__ int sCb; __shared__ u64 sSa;
    __shared__ u64 sP;
    __shared__ u32 sTc, sTsKey, sMt, sCntb;
    __shared__ float sInv;

    const float rinv = 1.0f / temps[row];
    const float4* R4 = (const float4*)(probs + (size_t)row * VOCAB);

    // ---- pass A: L1 hist, bucket = key >> 20 (4096 buckets)
    for (int i = tid; i < 4096; i += 1024) h1[i] = 0ull;
    __syncthreads();
    for (int i = 0; i < 32; ++i) {
        int j = tid + i * 1024;
        if (j < 32000) {
            float4 x = R4[j];
            float xs[4] = {x.x, x.y, x.z, x.w};
#pragma unroll
            for (int c = 0; c < 4; ++c) {
                u32 key = mono32(__float_as_uint(xs[c]));
                atomicAdd(&h1[key >> 20], fixmass(rv_of(xs[c], rinv)));
            }
        }
    }
    __syncthreads();
    // total S -> P
    {
        u64 s = h1[tid] + h1[tid + 1024] + h1[tid + 2048] + h1[tid + 3072];
        for (int o = 32; o >= 1; o >>= 1) s += __shfl_xor(s, o, 64);
        if ((tid & 63) == 0) wredu[tid >> 6] = s;
    }
    __syncthreads();
    if (tid == 0) {
        u64 S = 0ull;
        for (int w2 = 0; w2 < 16; ++w2) S += wredu[w2];
        sP = (u64)((double)topps[row] * (double)S);
    }
    __syncthreads();
    const u64 P = sP;
    if (tid < 64) scan_desc_u64(h1, 4096, 0ull, P, &sCb, &sSa);
    __syncthreads();
    const u32 cb1 = (u32)sCb; const u64 carry1 = sSa;
    __syncthreads();

    // ---- pass B: L2 hist among key>>20 == cb1, bucket = (key>>10)&1023
    h1[tid] = 0ull;
    __syncthreads();
    for (int i = 0; i < 32; ++i) {
        int j = tid + i * 1024;
        if (j < 32000) {
            float4 x = R4[j];
            float xs[4] = {x.x, x.y, x.z, x.w};
#pragma unroll
            for (int c = 0; c < 4; ++c) {
                u32 key = mono32(__float_as_uint(xs[c]));
                if ((key >> 20) == cb1)
                    atomicAdd(&h1[(key >> 10) & 1023u], fixmass(rv_of(xs[c], rinv)));
            }
        }
    }
    __syncthreads();
    if (tid < 64) scan_desc_u64(h1, 1024, carry1, P, &sCb, &sSa);
    __syncthreads();
    const u32 cb2 = (u32)sCb; const u64 carry2 = sSa;
    __syncthreads();

    // ---- pass C: L3 hist among key>>10 == (cb1<<10)|cb2, bucket = key&1023
    const u32 pref2 = (cb1 << 10) | cb2;
    h1[tid] = 0ull; c3[tid] = 0u;
    __syncthreads();
    for (int i = 0; i < 32; ++i) {
        int j = tid + i * 1024;
        if (j < 32000) {
            float4 x = R4[j];
            float xs[4] = {x.x, x.y, x.z, x.w};
#pragma unroll
            for (int c = 0; c < 4; ++c) {
                u32 key = mono32(__float_as_uint(xs[c]));
                if ((key >> 10) == pref2) {
                    atomicAdd(&h1[key & 1023u], fixmass(rv_of(xs[c], rinv)));
                    atomicAdd(&c3[key & 1023u], 1u);
                }
            }
        }
    }
    __syncthreads();
    if (tid < 64) scan_desc_u64(h1, 1024, carry2, P, &sCb, &sSa);
    __syncthreads();
    if (tid == 0) {
        const int cb3 = sCb; const u64 sa3 = sSa;
        u32 ts = (pref2 << 10) | (u32)cb3;
        u32 cntb = c3[cb3]; if (cntb == 0u) cntb = 1u;
        u64 tfq = fixmass(rv_of(unmono32(ts), rinv));
        u64 rem = P - sa3;
        u32 mt;
        if (tfq == 0ull) mt = cntb;
        else {
            u64 q = rem / tfq;
            mt = (q >= (u64)(cntb - 1)) ? cntb : ((u32)q + 1u);
        }
        u64 Spq = sa3 + (u64)mt * tfq;
        sTsKey = ts; sMt = mt; sCntb = cntb;
        sInv = (float)(1073741824.0 / (double)Spq);
        sTc = 0u;
    }
    __syncthreads();
    const u32 ts = sTsKey, mt = sMt, cntb = sCntb;

    // ---- pass D (rare): tie-index ranking when the cut splits a tie group
    if (mt < cntb) {
        for (int i = 0; i < 32; ++i) {
            int j = tid + i * 1024;
            if (j < 32000) {
                float4 x = R4[j];
                float xs[4] = {x.x, x.y, x.z, x.w};
#pragma unroll
                for (int c = 0; c < 4; ++c) {
                    u32 key = mono32(__float_as_uint(xs[c]));
                    if (key == ts) {
                        u32 pos = atomicAdd(&sTc, 1u);
                        if (pos < 1024u) tlist[pos] = (u32)(j * 4 + c);
                    }
                }
            }
        }
        __syncthreads();
        const u32 tn = min(sTc, 1024u);
        if ((u32)tid < tn) {
            u32 my = tlist[tid];
            u32 rank = 0;
            for (u32 j2 = 0; j2 < tn; ++j2) rank += (tlist[j2] < my) ? 1u : 0u;
            if (rank < mt) tieKept[(size_t)row * 1024 + rank] = my;
        }
        if (tid == 0) scTieN[row] = min(mt, tn);
    } else {
        if (tid == 0) scTieN[row] = TIE_ALL;   // keep every key==ts element
    }
    if (tid == 0) {
        scTs[row] = ts;
        scInvSp[row] = sInv;
        argmax[row] = 0ull;
    }
}

// K5: write probs_f + gumbel-argmax (exp/gumbel only for kept elems)
__global__ __launch_bounds__(512) void final2_kernel(
        float* __restrict__ probs, const float* __restrict__ temps,
        const u32* __restrict__ scTs, const u32* __restrict__ scTieN,
        const float* __restrict__ scInvSp, const u32* __restrict__ tieKept,
        u64* __restrict__ argmax) {
    const int row = blockIdx.y, hb = blockIdx.x, tid = (int)threadIdx.x;
    __shared__ u32 tl[1024];
    __shared__ u64 wbest[8];
    const u32 ts = scTs[row], tieN = scTieN[row];
    const u32 tlN = (tieN == TIE_ALL) ? 0u : tieN;
    const float invSp = scInvSp[row];
    const float rinv = 1.0f / temps[row];
    for (u32 i = tid; i < tlN; i += 512) tl[i] = tieKept[(size_t)row * 1024 + i];
    __syncthreads();
    float4* R4 = (float4*)(probs + (size_t)row * VOCAB);
    const u32 rowBase = (u32)row * (u32)VOCAB;
    const int base4 = hb * 8000;
    u64 best = 0ull;
    for (int i = 0; i < 16; ++i) {
        int j = tid + i * 512;
        if (j < 8000) {
            float4 x = R4[base4 + j];
            float xs[4] = {x.x, x.y, x.z, x.w};
            float4 out;
            float* op = (float*)&out;
#pragma unroll
            for (int c = 0; c < 4; ++c) {
                u32 key = mono32(__float_as_uint(xs[c]));
                u32 v = (u32)((base4 + j) * 4 + c);
                bool kept = key > ts;
                if (key == ts) {
                    if (tieN == TIE_ALL) {
                        kept = true;
                    } else {
                        kept = false;
                        for (u32 q2 = 0; q2 < tlN; ++q2)
                            if (tl[q2] == v) { kept = true; break; }
                    }
                }
                if (kept) {
                    float pf = rv_of(xs[c], rinv) * invSp;
                    op[c] = pf;
                    float g = jax_gumbel(jax_bits(rowBase + v));
                    float val = __logf(pf + 1e-20f) + g;
                    u64 pk = ((u64)mono32(__float_as_uint(val)) << 32) | (u32)(~v);
                    if (pk > best) best = pk;
                } else {
                    op[c] = 0.0f;
                }
            }
            R4[base4 + j] = out;
        }
    }
    for (int o = 32; o >= 1; o >>= 1) {
        u64 ob = __shfl_xor(best, o, 64);
        if (ob > best) best = ob;
    }
    if ((tid & 63) == 0) wbest[tid >> 6] = best;
    __syncthreads();
    if (tid == 0) {
        u64 b = wbest[0];
        for (int w2 = 1; w2 < 8; ++w2) if (wbest[w2] > b) b = wbest[w2];
        atomicMax(&argmax[row], b);
    }
}

// K6: token write
__global__ void token_kernel(const u64* __restrict__ argmax, float* __restrict__ outTok) {
    int n = (int)threadIdx.x;
    if (n < N_TOK) outTok[n] = (float)(~(u32)argmax[n]);
}

// ============== OLD fused per-row sampler (r5 verified; ws fallback) ========
__device__ __forceinline__ void scan_desc_wave(const float* h, int nb, float carry,
                                               float P, int* outCb, float* outSa) {
    int lane = (int)threadIdx.x & 63;
    int chunk = nb >> 6;
    int top = nb - 1 - lane * chunk;
    float ls = 0.0f;
    for (int j = 0; j < chunk; ++j) ls += h[top - j];
    float incl = ls;
    for (int o = 1; o < 64; o <<= 1) {
        float v = __shfl_up(incl, o, 64);
        if (lane >= o) incl += v;
    }
    float s0 = carry + incl - ls;
    unsigned long long mask = __ballot(s0 + ls > P);
    if (mask == 0ull) {
        if (lane == 63) { *outCb = 0; *outSa = carry + incl - h[0]; }
    } else {
        int cstar = (int)__builtin_ctzll(mask);
        if (lane == cstar) {
            float sa = s0; int cb = 0;
            for (int j = 0; j < chunk; ++j) {
                int b = top - j;
                if (sa + h[b] > P) { cb = b; break; }
                sa += h[b];
            }
            *outCb = cb; *outSa = sa;
        }
    }
}

__global__ __launch_bounds__(1024) void sample_kernel(
        float* __restrict__ probs, const float* __restrict__ temps,
        const float* __restrict__ topps, float* __restrict__ outTok) {
    const int row = blockIdx.x;
    const int tid = (int)threadIdx.x;
    float* L = probs + (long long)row * VOCAB;
    const float4* L4 = (const float4*)L;
    float4* L4w = (float4*)L;

    __shared__ float waveH[16][2048];
    __shared__ float hsum[2048];
    __shared__ uint32_t hcnt[1024];
    __shared__ float wred[16];
    __shared__ float aVal[16];
    __shared__ int aIdx[16];
    __shared__ uint32_t tieList[256];
    __shared__ int sCb;
    __shared__ float sSa;
    __shared__ float sP, sCarry1, sCarry2, sSp, sInvSp;
    __shared__ uint32_t sPref1, sCb2, sTsKey, sMt, sTieN, sCnt;
    uint32_t* keys = (uint32_t*)&waveH[4][0];

    const float t = temps[row];
    const float p = topps[row];
    const float rinv = 1.0f / t;

    for (int i = tid; i < 16 * 2048; i += 1024) ((float*)waveH)[i] = 0.0f;
    __syncthreads();
    {
        float* myH = waveH[tid >> 6];
#pragma unroll 2
        for (int i = 0; i < 31; ++i) {
            float4 x = L4[tid + i * 1024];
            float r0 = rv_of(x.x, rinv), r1 = rv_of(x.y, rinv);
            float r2 = rv_of(x.z, rinv), r3 = rv_of(x.w, rinv);
            atomicAdd(&myH[__float_as_uint(r0) >> 20], r0);
            atomicAdd(&myH[__float_as_uint(r1) >> 20], r1);
            atomicAdd(&myH[__float_as_uint(r2) >> 20], r2);
            atomicAdd(&myH[__float_as_uint(r3) >> 20], r3);
        }
        if (tid < 256) {
            float4 x = L4[31744 + tid];
            float r0 = rv_of(x.x, rinv), r1 = rv_of(x.y, rinv);
            float r2 = rv_of(x.z, rinv), r3 = rv_of(x.w, rinv);
            atomicAdd(&myH[__float_as_uint(r0) >> 20], r0);
            atomicAdd(&myH[__float_as_uint(r1) >> 20], r1);
            atomicAdd(&myH[__float_as_uint(r2) >> 20], r2);
            atomicAdd(&myH[__float_as_uint(r3) >> 20], r3);
        }
    }
    __syncthreads();
    {
        float a0 = 0.0f, a1 = 0.0f;
#pragma unroll
        for (int w2 = 0; w2 < 16; ++w2) { a0 += waveH[w2][tid]; a1 += waveH[w2][tid + 1024]; }
        hsum[tid] = a0; hsum[tid + 1024] = a1;
        float s = a0 + a1;
        for (int o = 32; o >= 1; o >>= 1) s += __shfl_xor(s, o, 64);
        if ((tid & 63) == 0) wred[tid >> 6] = s;
    }
    __syncthreads();
    if (tid == 0) {
        float tot = 0.0f;
        for (int w2 = 0; w2 < 16; ++w2) tot += wred[w2];
        sP = p * tot;
    }
    __syncthreads();
    if (tid < 64) scan_desc_wave(hsum, 2048, 0.0f, sP, &sCb, &sSa);
    __syncthreads();
    if (tid == 0) { sPref1 = (uint32_t)sCb; sCarry1 = sSa; sCnt = 0u; }
    __syncthreads();

    const uint32_t pref1 = sPref1;
    const float P = sP;
#pragma unroll 2
    for (int i = 0; i < 31; ++i) {
        float4 x = L4[tid + i * 1024];
        float rr[4] = {rv_of(x.x, rinv), rv_of(x.y, rinv), rv_of(x.z, rinv), rv_of(x.w, rinv)};
#pragma unroll
        for (int c = 0; c < 4; ++c) {
            uint32_t key = __float_as_uint(rr[c]);
            if ((key >> 20) == pref1) {
                uint32_t pos = atomicAdd(&sCnt, 1u);
                if (pos < LIST_CAP) keys[pos] = key;
            }
        }
    }
    if (tid < 256) {
        float4 x = L4[31744 + tid];
        float rr[4] = {rv_of(x.x, rinv), rv_of(x.y, rinv), rv_of(x.z, rinv), rv_of(x.w, rinv)};
#pragma unroll
        for (int c = 0; c < 4; ++c) {
            uint32_t key = __float_as_uint(rr[c]);
            if ((key >> 20) == pref1) {
                uint32_t pos = atomicAdd(&sCnt, 1u);
                if (pos < LIST_CAP) keys[pos] = key;
            }
        }
    }
    __syncthreads();
    const uint32_t K = sCnt;
    const bool inLds = (K <= LIST_CAP);

    if (tid < 1024) hsum[tid] = 0.0f;
    __syncthreads();
    if (inLds) {
        for (uint32_t j = tid; j < K; j += 1024) {
            uint32_t key = keys[j];
            atomicAdd(&hsum[(key >> 10) & 1023u], __uint_as_float(key));
        }
    } else {
        for (int i = 0; i < 125; ++i) {
            int v = tid + i * 1024;
            float rv = rv_of(L[v], rinv);
            uint32_t key = __float_as_uint(rv);
            if ((key >> 20) == pref1) atomicAdd(&hsum[(key >> 10) & 1023u], rv);
        }
    }
    __syncthreads();
    if (tid < 64) scan_desc_wave(hsum, 1024, sCarry1, P, &sCb, &sSa);
    __syncthreads();
    if (tid == 0) { sCb2 = (uint32_t)sCb; sCarry2 = sSa; }
    __syncthreads();

    const uint32_t cb2 = sCb2;
    if (tid < 1024) { hsum[tid] = 0.0f; hcnt[tid] = 0u; }
    __syncthreads();
    if (inLds) {
        for (uint32_t j = tid; j < K; j += 1024) {
            uint32_t key = keys[j];
            if (((key >> 10) & 1023u) == cb2) {
                atomicAdd(&hsum[key & 1023u], __uint_as_float(key));
                atomicAdd(&hcnt[key & 1023u], 1u);
            }
        }
    } else {
        const uint32_t pref2full = (pref1 << 10) | cb2;
        for (int i = 0; i < 125; ++i) {
            int v = tid + i * 1024;
            float rv = rv_of(L[v], rinv);
            uint32_t key = __float_as_uint(rv);
            if ((key >> 10) == pref2full) {
                atomicAdd(&hsum[key & 1023u], rv);
                atomicAdd(&hcnt[key & 1023u], 1u);
            }
        }
    }
    __syncthreads();
    if (tid < 64) scan_desc_wave(hsum, 1024, sCarry2, P, &sCb, &sSa);
    __syncthreads();
    if (tid == 0) {
        int cb3 = sCb; float sa3 = sSa;
        uint32_t ts = (pref1 << 20) | (cb2 << 10) | (uint32_t)cb3;
        uint32_t cnt = hcnt[cb3]; if (cnt == 0u) cnt = 1u;
        float tf = __uint_as_float(ts);
        uint32_t mt;
        float rem = P - sa3; if (rem < 0.0f) rem = 0.0f;
        if (!(tf > 0.0f)) mt = cnt;
        else {
            float q = floorf(rem / tf);
            mt = (q >= (float)(cnt - 1)) ? cnt : ((uint32_t)q + 1u);
        }
        sTsKey = ts; sMt = mt;
        sSp = sa3 + (float)mt * tf;
        sInvSp = 1.0f / sSp;
        sTieN = 0u;
    }
    __syncthreads();

    const uint32_t ts = sTsKey, mt = sMt;
    const float invSp = sInvSp;
    float bestV = -INFINITY;
    int bestI = 0x7FFFFFFF;
    const uint32_t rowBase = (uint32_t)row * (uint32_t)VOCAB;
    for (int i = 0; i < 32; ++i) {
        int f4i = (i < 31) ? (tid + i * 1024) : (31744 + tid);
        if (i == 31 && tid >= 256) break;
        float4 x = L4[f4i];
        float rr[4] = {rv_of(x.x, rinv), rv_of(x.y, rinv), rv_of(x.z, rinv), rv_of(x.w, rinv)};
        float4 out;
        float* op = (float*)&out;
#pragma unroll
        for (int c = 0; c < 4; ++c) {
            uint32_t key = __float_as_uint(rr[c]);
            int v = f4i * 4 + c;
            if (key > ts) {
                float pf = rr[c] * invSp;
                op[c] = pf;
                float g = jax_gumbel(jax_bits(rowBase + (uint32_t)v));
                float val = __logf(pf + 1e-20f) + g;
                if (val > bestV || (val == bestV && v < bestI)) { bestV = val; bestI = v; }
            } else if (key == ts) {
                op[c] = 0.0f;
                uint32_t pos = atomicAdd(&sTieN, 1u);
                if (pos < 256u) tieList[pos] = (uint32_t)v;
            } else {
                op[c] = 0.0f;
            }
        }
        L4w[f4i] = out;
    }
    __syncthreads();
    {
        const uint32_t tn = min(sTieN, 256u);
        if ((uint32_t)tid < tn) {
            uint32_t v = tieList[tid];
            uint32_t rank = 0;
            for (uint32_t j = 0; j < tn; ++j) rank += (tieList[j] < v) ? 1u : 0u;
            if (rank < mt) {
                float pf = __uint_as_float(ts) * invSp;
                L[v] = pf;
                float g = jax_gumbel(jax_bits(rowBase + v));
                float val = __logf(pf + 1e-20f) + g;
                if (val > bestV || (val == bestV && (int)v < bestI)) { bestV = val; bestI = (int)v; }
            }
        }
    }
    for (int o = 32; o >= 1; o >>= 1) {
        float ov = __shfl_xor(bestV, o, 64);
        int oi = __shfl_xor(bestI, o, 64);
        if (ov > bestV || (ov == bestV && oi < bestI)) { bestV = ov; bestI = oi; }
    }
    if ((tid & 63) == 0) { aVal[tid >> 6] = bestV; aIdx[tid >> 6] = bestI; }
    __syncthreads();
    if (tid == 0) {
        float bv = aVal[0]; int bi = aIdx[0];
        for (int w2 = 1; w2 < 16; ++w2) {
            if (aVal[w2] > bv || (aVal[w2] == bv && aIdx[w2] < bi)) { bv = aVal[w2]; bi = aIdx[w2]; }
        }
        outTok[row] = (float)bi;
    }
}

// ===================== launch =====================
extern "C" void kernel_launch(void* const* d_in, const int* in_sizes, int n_in,
                              void* d_out, int out_size, void* d_ws, size_t ws_size,
                              hipStream_t stream) {
    const float* hidden = (const float*)d_in[0];
    const float* emb    = (const float*)d_in[1];
    const float* temps  = (const float*)d_in[2];
    const float* topps  = (const float*)d_in[3];
    const int*   idx    = (const int*)d_in[4];

    float* probs  = (float*)d_out;        // [N,V]: logits, then probs_f in place
    float* outTok = probs + NV_ELEMS;     // [N] tokens as f32

    char* ws = (char*)d_ws;
    const bool wsGemm = ws_size >= (size_t)(1u << 20);
    const bool wsBig  = ws_size >= (size_t)(4u << 20);

    if (wsGemm) {
        ushort* wsA = (ushort*)ws;        // 32 x 32 KB pre-swizzled A images
        prep_a<<<N_TOK, 256, 0, stream>>>(hidden, idx, wsA);
        gemm_mfma<<<VOCAB / 64, 256, 0, stream>>>(wsA, emb, probs);
    } else {
        gemm_kernel<<<dim3(4, 2000), 256, 0, stream>>>(hidden, idx, emb, probs);
    }

    if (wsBig) {
        char* m        = ws + (2u << 20);
        u32* scTs      = (u32*)(m);                 // 1 KB
        u32* scTieN    = (u32*)(m + 1024);          // 1 KB
        float* scInvSp = (float*)(m + 2048);        // 1 KB
        u64* argmax    = (u64*)(m + 3072);          // 2 KB
        u32* tieKept   = (u32*)(m + 8192);          // 1 MB

        resolveC_kernel<<<N_TOK, 1024, 0, stream>>>(probs, temps, topps,
                                                    scTs, scTieN, scInvSp,
                                                    tieKept, argmax);
        final2_kernel<<<dim3(4, N_TOK), 512, 0, stream>>>(probs, temps, scTs, scTieN,
                                                          scInvSp, tieKept, argmax);
        token_kernel<<<1, 256, 0, stream>>>(argmax, outTok);
    } else {
        sample_kernel<<<N_TOK, 1024, 0, stream>>>(probs, temps, topps, outTok);
    }
}

// Round 15
// 430.032 us; speedup vs baseline: 1.1358x; 1.0091x over previous
//
#include <hip/hip_runtime.h>
#include <stdint.h>

#define N_TOK 256
#define D_MODEL 1024
#define VOCAB 128000
#define NV_ELEMS (256LL * 128000LL)
#define LIST_CAP 24576      // fallback sampler list cap
#define KCAP 24576          // resolveC in-LDS key list cap (96 KB)
#define TIE_ALL 0xFFFFFFFFu // sentinel: every key==ts element is kept

typedef unsigned long long u64;
typedef uint32_t u32;
typedef __attribute__((ext_vector_type(8))) short bfrag;   // 8 bf16 (4 VGPR)
typedef __attribute__((ext_vector_type(4))) float facc;    // 4 f32

// ===================== helpers =====================
__device__ __forceinline__ uint32_t bf16_rne_bits(float x) {
    uint32_t u = __float_as_uint(x);
    return (u + 0x7fffu + ((u >> 16) & 1u)) >> 16;
}

__device__ __forceinline__ uint32_t rotl32(uint32_t x, int d) {
    return (x << d) | (x >> (32 - d));
}

// monotone key for f32 bits (order-preserving over all finite floats)
__device__ __forceinline__ u32 mono32(u32 b) {
    return (b & 0x80000000u) ? ~b : (b | 0x80000000u);
}
__device__ __forceinline__ float unmono32(u32 k) {
    u32 b = (k & 0x80000000u) ? (k & 0x7FFFFFFFu) : ~k;
    return __uint_as_float(b);
}

// fixed-point mass: rv * 2^30 (u64). order-independent integer sums.
__device__ __forceinline__ u64 fixmass(float rv) {
    return (u64)(rv * 1073741824.0f);
}

// JAX threefry2x32, key=(0,42) (KAT-verified core)
__device__ __forceinline__ uint2 tf_0_42(uint32_t c0, uint32_t c1) {
    const uint32_t ks0 = 0u, ks1 = 42u, ks2 = 0x1BD11BDAu ^ 42u;
    uint32_t x0 = c0 + ks0, x1 = c1 + ks1;
#define R4(a,b,c,d) \
    x0 += x1; x1 = rotl32(x1,a); x1 ^= x0; \
    x0 += x1; x1 = rotl32(x1,b); x1 ^= x0; \
    x0 += x1; x1 = rotl32(x1,c); x1 ^= x0; \
    x0 += x1; x1 = rotl32(x1,d); x1 ^= x0;
    R4(13,15,26,6)   x0 += ks1; x1 += ks2 + 1u;
    R4(17,29,16,24)  x0 += ks2; x1 += ks0 + 2u;
    R4(13,15,26,6)   x0 += ks0; x1 += ks1 + 3u;
    R4(17,29,16,24)  x0 += ks1; x1 += ks2 + 4u;
    R4(13,15,26,6)   x0 += ks2; x1 += ks0 + 5u;
#undef R4
    return make_uint2(x0, x1);
}

// partitionable threefry bits: counter=(0,j), out = x^y (verified r3)
__device__ __forceinline__ uint32_t jax_bits(uint32_t j) {
    uint2 r = tf_0_42(0u, j);
    return r.x ^ r.y;
}

__device__ __forceinline__ float jax_gumbel(uint32_t bits) {
    const float TINY = 1.17549435e-38f;
    float u = __uint_as_float((bits >> 9) | 0x3f800000u) - 1.0f;
    u = u + TINY;
    u = fmaxf(TINY, u);
    return -__logf(-__logf(u));
}

__device__ __forceinline__ float rv_of(float l, float rinv) {
    return __expf(l * rinv);
}

// async 16B global->LDS (dest = lbase + lane*16)
__device__ __forceinline__ void async_copy16(const void* g, void* lbase, int lane) {
#if defined(__has_builtin) && __has_builtin(__builtin_amdgcn_global_load_lds)
    __builtin_amdgcn_global_load_lds((const uint32_t*)g, (uint32_t*)lbase, 16, 0, 0);
#else
    *(bfrag*)((char*)lbase + lane * 16) = *(const bfrag*)g;
#endif
}

// descending-bucket scan, one wave (lanes 0..63), exact u64 arithmetic
__device__ __forceinline__ void scan_desc_u64(const u64* h, int nb, u64 carry, u64 P,
                                              int* outCb, u64* outSa) {
    int lane = (int)threadIdx.x & 63;
    int chunk = nb >> 6;
    int top = nb - 1 - lane * chunk;
    u64 ls = 0ull;
    for (int j = 0; j < chunk; ++j) ls += h[top - j];
    u64 incl = ls;
    for (int o = 1; o < 64; o <<= 1) {
        u64 v = __shfl_up(incl, o, 64);
        if (lane >= o) incl += v;
    }
    u64 s0 = carry + incl - ls;
    unsigned long long mask = __ballot(s0 + ls > P);
    if (mask == 0ull) {
        if (lane == 0) { *outCb = 0; *outSa = carry; }   // cannot happen (P < total)
    } else {
        int cstar = (int)__builtin_ctzll(mask);
        if (lane == cstar) {
            u64 sa = s0; int cb = 0;
            for (int j = 0; j < chunk; ++j) {
                int b = top - j;
                if (sa + h[b] > P) { cb = b; break; }
                sa += h[b];
            }
            *outCb = cb; *outSa = sa;
        }
    }
}

// ============ A pre-convert (gather + split-bf16 + swizzled image, BK=32) ====
__global__ __launch_bounds__(256) void prep_a(
        const float* __restrict__ hidden, const int* __restrict__ idx,
        ushort* __restrict__ wsA) {
    const int m = blockIdx.x;
    const int t = threadIdx.x;
    const float* src = hidden + (long long)idx[m] * D_MODEL;
    const uint32_t swz = (uint32_t)((m & 7) << 4);
    for (int j = 0; j < 4; ++j) {
        int k = t * 4 + j;
        float x = src[k];
        uint32_t hb = bf16_rne_bits(x);
        float hf = __uint_as_float(hb << 16);
        uint32_t lb = bf16_rne_bits(x - hf);
        int kt = k >> 5, kk = k & 31, g = kk >> 3, e = kk & 7;
        char* img = (char*)wsA + (size_t)kt * 32768;
        uint32_t base = (uint32_t)(m * 128 + g * 32);
        *(ushort*)(img + ((base + 0) ^ swz) + e * 2) = (ushort)hb;
        *(ushort*)(img + ((base + 16) ^ swz) + e * 2) = (ushort)lb;
    }
}

// ===== split-bf16 MFMA GEMM — r5/r10/r13 measured-best (BM=256,BN=64,BK=32,
// 4 waves, 40 KB LDS; 894 TF-equiv = the 2-barrier structural ceiling) =====
__global__ __launch_bounds__(256) void gemm_mfma(
        const ushort* __restrict__ wsA, const float* __restrict__ emb,
        float* __restrict__ logits) {
    __shared__ __align__(16) ushort Aimg[16384];  // 32 KB swizzled A K-tile
    __shared__ __align__(16) ushort Bimg[4096];   // 8 KB swizzled B K-tile
    const int tid = (int)threadIdx.x;
    const int w = tid >> 6, l = tid & 63;
    const int lr = l & 15, lg = l >> 4;
    const int v0 = blockIdx.x * 64;
    char* Ab = (char*)Aimg;
    char* Bb = (char*)Bimg;

    facc acc[4][4] = {};

    for (int kt = 0; kt < 32; ++kt) {
        __syncthreads();
        const char* asrc = (const char*)wsA + (size_t)kt * 32768;
#pragma unroll
        for (int i = 0; i < 8; ++i) {
            int off = w * 8192 + i * 1024;
            async_copy16(asrc + off + l * 16, Ab + off, l);
        }
        {
            int rb = tid >> 2, g = tid & 3;
            const float* bs = emb + (size_t)(v0 + rb) * D_MODEL + kt * 32 + g * 8;
            float4 x0 = *(const float4*)bs;
            float4 x1 = *(const float4*)(bs + 4);
            float xs[8] = {x0.x, x0.y, x0.z, x0.w, x1.x, x1.y, x1.z, x1.w};
            bfrag h, lo;
#pragma unroll
            for (int e = 0; e < 8; ++e) {
                uint32_t hb = bf16_rne_bits(xs[e]);
                float hf = __uint_as_float(hb << 16);
                uint32_t lb = bf16_rne_bits(xs[e] - hf);
                h[e] = (short)hb; lo[e] = (short)lb;
            }
            uint32_t swz = (uint32_t)((rb & 7) << 4);
            uint32_t base = (uint32_t)(rb * 128 + g * 32);
            *(bfrag*)(Bb + ((base + 0) ^ swz)) = h;
            *(bfrag*)(Bb + ((base + 16) ^ swz)) = lo;
        }
        __syncthreads();
        bfrag bh[4], bl[4];
#pragma unroll
        for (int nj = 0; nj < 4; ++nj) {
            int rb = nj * 16 + lr;
            uint32_t swz = (uint32_t)((rb & 7) << 4);
            uint32_t base = (uint32_t)(rb * 128 + lg * 32);
            bh[nj] = *(const bfrag*)(Bb + ((base + 0) ^ swz));
            bl[nj] = *(const bfrag*)(Bb + ((base + 16) ^ swz));
        }
#pragma unroll
        for (int mi = 0; mi < 4; ++mi) {
            int r = w * 64 + mi * 16 + lr;
            uint32_t swz = (uint32_t)((r & 7) << 4);
            uint32_t base = (uint32_t)(r * 128 + lg * 32);
            bfrag ah = *(const bfrag*)(Ab + ((base + 0) ^ swz));
            bfrag al = *(const bfrag*)(Ab + ((base + 16) ^ swz));
#pragma unroll
            for (int nj = 0; nj < 4; ++nj) {
                acc[mi][nj] = __builtin_amdgcn_mfma_f32_16x16x32_bf16(ah, bh[nj], acc[mi][nj], 0, 0, 0);
                acc[mi][nj] = __builtin_amdgcn_mfma_f32_16x16x32_bf16(ah, bl[nj], acc[mi][nj], 0, 0, 0);
                acc[mi][nj] = __builtin_amdgcn_mfma_f32_16x16x32_bf16(al, bh[nj], acc[mi][nj], 0, 0, 0);
            }
        }
    }
#pragma unroll
    for (int mi = 0; mi < 4; ++mi) {
        int mbase = w * 64 + mi * 16 + lg * 4;
#pragma unroll
        for (int nj = 0; nj < 4; ++nj) {
            int v = v0 + nj * 16 + lr;
#pragma unroll
            for (int reg = 0; reg < 4; ++reg)
                logits[(size_t)(mbase + reg) * VOCAB + v] = acc[mi][nj][reg];
        }
    }
}

// ===================== f32 GEMM fallback (ws too small) =====================
__global__ __launch_bounds__(256) void gemm_kernel(
        const float* __restrict__ hidden, const int* __restrict__ idx,
        const float* __restrict__ emb, float* __restrict__ logits) {
    __shared__ float As[16][64];
    __shared__ float Bs[16][64];
    const int n0 = blockIdx.x * 64, v0 = blockIdx.y * 64;
    const int tid = threadIdx.x;
    const int tx = tid & 15, ty = tid >> 4;
    const int lr = tid >> 2, lk = (tid & 3) * 4;
    float acc[4][4] = {};
    const long long aRow = (long long)idx[n0 + lr] * D_MODEL + lk;
    const long long bRow = (long long)(v0 + lr) * D_MODEL + lk;
    for (int k0 = 0; k0 < D_MODEL; k0 += 16) {
        float4 av = *(const float4*)(hidden + aRow + k0);
        float4 bv = *(const float4*)(emb + bRow + k0);
        __syncthreads();
        As[lk + 0][lr] = av.x; As[lk + 1][lr] = av.y; As[lk + 2][lr] = av.z; As[lk + 3][lr] = av.w;
        Bs[lk + 0][lr] = bv.x; Bs[lk + 1][lr] = bv.y; Bs[lk + 2][lr] = bv.z; Bs[lk + 3][lr] = bv.w;
        __syncthreads();
#pragma unroll
        for (int kk = 0; kk < 16; ++kk) {
            float4 a = *(const float4*)&As[kk][ty * 4];
            float4 b = *(const float4*)&Bs[kk][tx * 4];
            float aa[4] = {a.x, a.y, a.z, a.w};
            float bb[4] = {b.x, b.y, b.z, b.w};
#pragma unroll
            for (int i = 0; i < 4; ++i)
#pragma unroll
                for (int j = 0; j < 4; ++j)
                    acc[i][j] += aa[i] * bb[j];
        }
    }
#pragma unroll
    for (int i = 0; i < 4; ++i) {
        float4 o = make_float4(acc[i][0], acc[i][1], acc[i][2], acc[i][3]);
        *(float4*)(logits + (long long)(n0 + ty * 4 + i) * VOCAB + (v0 + tx * 4)) = o;
    }
}

// ========== resolveC: per-row top-p resolve, 2 full passes ==========
// Pass A: L1 hist (4-way replicated vs hot-bucket LDS-atomic serialization).
// Pass B: L2 hist + ballot-compact cut-bucket keys into 96 KB LDS list
//         (1 atomic per wave-group; exact total count regardless of cap).
// L3 from the in-LDS list (no 3rd row pass); full-row fallback if count>KCAP.
// Same u64 fixed-point math as r13/r14 -> bit-identical selection.
__global__ __launch_bounds__(1024) void resolveC_kernel(
        const float* __restrict__ probs, const float* __restrict__ temps,
        const float* __restrict__ topps,
        u32* __restrict__ scTs, u32* __restrict__ scTieN,
        float* __restrict__ scInvSp, u32* __restrict__ tieKept,
        u64* __restrict__ argmax) {
    const int row = blockIdx.x, tid = (int)threadIdx.x;
    __shared__ u64 hrep[4][4096];           // 128 KB; pass-B arrays alias it
    __shared__ u32 tlist[1024];
    __shared__ u64 wredu[16];
    __shared__ int sCb; __shared__ u64 sSa;
    __shared__ u64 sP;
    __shared__ u32 sCb1; __shared__ u64 sCarry1;
    __shared__ u32 sCb2; __shared__ u64 sCarry2;
    __shared__ u32 sListCnt, sTc, sTsKey, sMt, sCntb;
    __shared__ float sInv;

    u32* klist = (u32*)&hrep[0][0];                       // 96 KB  [0, 98304)
    u64* h2    = (u64*)((char*)&hrep[0][0] + 98304);      // 8 KB
    u32* c3    = (u32*)((char*)&hrep[0][0] + 106496);     // 4 KB

    const float rinv = 1.0f / temps[row];
    const float4* R4 = (const float4*)(probs + (size_t)row * VOCAB);
    const int lane = tid & 63;

    // ---- pass A: L1 hist, bucket = key >> 20, 4 replicas by wave
    for (int i = tid; i < 16384; i += 1024) ((u64*)hrep)[i] = 0ull;
    __syncthreads();
    {
        u64* myrep = hrep[(tid >> 6) & 3];
        for (int i = 0; i < 32; ++i) {
            int j = tid + i * 1024;
            if (j < 32000) {
                float4 x = R4[j];
                float xs[4] = {x.x, x.y, x.z, x.w};
#pragma unroll
                for (int c = 0; c < 4; ++c) {
                    u32 key = mono32(__float_as_uint(xs[c]));
                    atomicAdd(&myrep[key >> 20], fixmass(rv_of(xs[c], rinv)));
                }
            }
        }
    }
    __syncthreads();
    // merge replicas into hrep[0]
    for (int b = tid; b < 4096; b += 1024)
        hrep[0][b] += hrep[1][b] + hrep[2][b] + hrep[3][b];
    __syncthreads();
    // total S -> P
    {
        u64 s = hrep[0][tid] + hrep[0][tid + 1024] + hrep[0][tid + 2048] + hrep[0][tid + 3072];
        for (int o = 32; o >= 1; o >>= 1) s += __shfl_xor(s, o, 64);
        if (lane == 0) wredu[tid >> 6] = s;
    }
    __syncthreads();
    if (tid == 0) {
        u64 S = 0ull;
        for (int w2 = 0; w2 < 16; ++w2) S += wredu[w2];
        sP = (u64)((double)topps[row] * (double)S);
    }
    __syncthreads();
    const u64 P = sP;
    if (tid < 64) scan_desc_u64(hrep[0], 4096, 0ull, P, &sCb, &sSa);
    __syncthreads();
    if (tid == 0) { sCb1 = (u32)sCb; sCarry1 = sSa; sListCnt = 0u; }
    __syncthreads();
    const u32 cb1 = sCb1;
    // zero pass-B arrays (alias hrep; safe after cb1/carry1 extracted)
    h2[tid] = 0ull; c3[tid] = 0u;
    __syncthreads();

    // ---- pass B: L2 hist + ballot-compacted key list of the cut L1 bucket
    for (int i = 0; i < 32; ++i) {
        int j = tid + i * 1024;
        bool valid = j < 32000;
        float4 x = valid ? R4[j] : make_float4(0.f, 0.f, 0.f, 0.f);
        float xs[4] = {x.x, x.y, x.z, x.w};
#pragma unroll
        for (int c = 0; c < 4; ++c) {
            u32 key = mono32(__float_as_uint(xs[c]));
            bool m = valid && ((key >> 20) == cb1);
            if (m) atomicAdd(&h2[(key >> 10) & 1023u], fixmass(rv_of(xs[c], rinv)));
            unsigned long long grp = __ballot(m);
            if (m) {
                u32 prefix = (u32)__popcll(grp & ((1ull << lane) - 1ull));
                int leader = (int)__builtin_ctzll(grp);
                u32 base = 0u;
                if (lane == leader) base = atomicAdd(&sListCnt, (u32)__popcll(grp));
                base = (u32)__shfl((int)base, leader, 64);
                u32 pos = base + prefix;
                if (pos < KCAP) klist[pos] = key;
            }
        }
    }
    __syncthreads();
    const u32 listTotal = sListCnt;
    const bool inLds = listTotal <= (u32)KCAP;
    if (tid < 64) scan_desc_u64(h2, 1024, sCarry1, P, &sCb, &sSa);
    __syncthreads();
    if (tid == 0) { sCb2 = (u32)sCb; sCarry2 = sSa; }
    __syncthreads();
    const u32 cb2 = sCb2;
    const u32 pref2 = (cb1 << 10) | cb2;
    h2[tid] = 0ull; c3[tid] = 0u;
    __syncthreads();

    // ---- L3 hist: from the in-LDS list (common) or a 3rd row pass (fallback)
    if (inLds) {
        for (u32 q = tid; q < listTotal; q += 1024) {
            u32 key = klist[q];
            if ((key >> 10) == pref2) {
                atomicAdd(&h2[key & 1023u], fixmass(rv_of(unmono32(key), rinv)));
                atomicAdd(&c3[key & 1023u], 1u);
            }
        }
    } else {
        for (int i = 0; i < 32; ++i) {
            int j = tid + i * 1024;
            if (j < 32000) {
                float4 x = R4[j];
                float xs[4] = {x.x, x.y, x.z, x.w};
#pragma unroll
                for (int c = 0; c < 4; ++c) {
                    u32 key = mono32(__float_as_uint(xs[c]));
                    if ((key >> 10) == pref2) {
                        atomicAdd(&h2[key & 1023u], fixmass(rv_of(xs[c], rinv)));
                        atomicAdd(&c3[key & 1023u], 1u);
                    }
                }
            }
        }
    }
    __syncthreads();
    if (tid < 64) scan_desc_u64(h2, 1024, sCarry2, P, &sCb, &sSa);
    __syncthreads();
    if (tid == 0) {
        const int cb3 = sCb; const u64 sa3 = sSa;
        u32 ts = (pref2 << 10) | (u32)cb3;
        u32 cntb = c3[cb3]; if (cntb == 0u) cntb = 1u;
        u64 tfq = fixmass(rv_of(unmono32(ts), rinv));
        u64 rem = P - sa3;
        u32 mt;
        if (tfq == 0ull) mt = cntb;
        else {
            u64 q = rem / tfq;
            mt = (q >= (u64)(cntb - 1)) ? cntb : ((u32)q + 1u);
        }
        u64 Spq = sa3 + (u64)mt * tfq;
        sTsKey = ts; sMt = mt; sCntb = cntb;
        sInv = (float)(1073741824.0 / (double)Spq);
        sTc = 0u;
    }
    __syncthreads();
    const u32 ts = sTsKey, mt = sMt, cntb = sCntb;

    // ---- tie ranking (rare): only when the cut splits a bit-identical group
    if (mt < cntb) {
        for (int i = 0; i < 32; ++i) {
            int j = tid + i * 1024;
            if (j < 32000) {
                float4 x = R4[j];
                float xs[4] = {x.x, x.y, x.z, x.w};
#pragma unroll
                for (int c = 0; c < 4; ++c) {
                    u32 key = mono32(__float_as_uint(xs[c]));
                    if (key == ts) {
                        u32 pos = atomicAdd(&sTc, 1u);
                        if (pos < 1024u) tlist[pos] = (u32)(j * 4 + c);
                    }
                }
            }
        }
        __syncthreads();
        const u32 tn = min(sTc, 1024u);
        if ((u32)tid < tn) {
            u32 my = tlist[tid];
            u32 rank = 0;
            for (u32 j2 = 0; j2 < tn; ++j2) rank += (tlist[j2] < my) ? 1u : 0u;
            if (rank < mt) tieKept[(size_t)row * 1024 + rank] = my;
        }
        if (tid == 0) scTieN[row] = min(mt, tn);
    } else {
        if (tid == 0) scTieN[row] = TIE_ALL;
    }
    if (tid == 0) {
        scTs[row] = ts;
        scInvSp[row] = sInv;
        argmax[row] = 0ull;
    }
}

// K5: write probs_f + gumbel-argmax (exp/gumbel only for kept elems)
__global__ __launch_bounds__(512) void final2_kernel(
        float* __restrict__ probs, const float* __restrict__ temps,
        const u32* __restrict__ scTs, const u32* __restrict__ scTieN,
        const float* __restrict__ scInvSp, const u32* __restrict__ tieKept,
        u64* __restrict__ argmax) {
    const int row = blockIdx.y, hb = blockIdx.x, tid = (int)threadIdx.x;
    __shared__ u32 tl[1024];
    __shared__ u64 wbest[8];
    const u32 ts = scTs[row], tieN = scTieN[row];
    const u32 tlN = (tieN == TIE_ALL) ? 0u : tieN;
    const float invSp = scInvSp[row];
    const float rinv = 1.0f / temps[row];
    for (u32 i = tid; i < tlN; i += 512) tl[i] = tieKept[(size_t)row * 1024 + i];
    __syncthreads();
    float4* R4 = (float4*)(probs + (size_t)row * VOCAB);
    const u32 rowBase = (u32)row * (u32)VOCAB;
    const int base4 = hb * 8000;
    u64 best = 0ull;
    for (int i = 0; i < 16; ++i) {
        int j = tid + i * 512;
        if (j < 8000) {
            float4 x = R4[base4 + j];
            float xs[4] = {x.x, x.y, x.z, x.w};
            float4 out;
            float* op = (float*)&out;
#pragma unroll
            for (int c = 0; c < 4; ++c) {
                u32 key = mono32(__float_as_uint(xs[c]));
                u32 v = (u32)((base4 + j) * 4 + c);
                bool kept = key > ts;
                if (key == ts) {
                    if (tieN == TIE_ALL) {
                        kept = true;
                    } else {
                        kept = false;
                        for (u32 q2 = 0; q2 < tlN; ++q2)
                            if (tl[q2] == v) { kept = true; break; }
                    }
                }
                if (kept) {
                    float pf = rv_of(xs[c], rinv) * invSp;
                    op[c] = pf;
                    float g = jax_gumbel(jax_bits(rowBase + v));
                    float val = __logf(pf + 1e-20f) + g;
                    u64 pk = ((u64)mono32(__float_as_uint(val)) << 32) | (u32)(~v);
                    if (pk > best) best = pk;
                } else {
                    op[c] = 0.0f;
                }
            }
            R4[base4 + j] = out;
        }
    }
    for (int o = 32; o >= 1; o >>= 1) {
        u64 ob = __shfl_xor(best, o, 64);
        if (ob > best) best = ob;
    }
    if ((tid & 63) == 0) wbest[tid >> 6] = best;
    __syncthreads();
    if (tid == 0) {
        u64 b = wbest[0];
        for (int w2 = 1; w2 < 8; ++w2) if (wbest[w2] > b) b = wbest[w2];
        atomicMax(&argmax[row], b);
    }
}

// K6: token write
__global__ void token_kernel(const u64* __restrict__ argmax, float* __restrict__ outTok) {
    int n = (int)threadIdx.x;
    if (n < N_TOK) outTok[n] = (float)(~(u32)argmax[n]);
}

// ============== OLD fused per-row sampler (r5 verified; ws fallback) ========
__device__ __forceinline__ void scan_desc_wave(const float* h, int nb, float carry,
                                               float P, int* outCb, float* outSa) {
    int lane = (int)threadIdx.x & 63;
    int chunk = nb >> 6;
    int top = nb - 1 - lane * chunk;
    float ls = 0.0f;
    for (int j = 0; j < chunk; ++j) ls += h[top - j];
    float incl = ls;
    for (int o = 1; o < 64; o <<= 1) {
        float v = __shfl_up(incl, o, 64);
        if (lane >= o) incl += v;
    }
    float s0 = carry + incl - ls;
    unsigned long long mask = __ballot(s0 + ls > P);
    if (mask == 0ull) {
        if (lane == 63) { *outCb = 0; *outSa = carry + incl - h[0]; }
    } else {
        int cstar = (int)__builtin_ctzll(mask);
        if (lane == cstar) {
            float sa = s0; int cb = 0;
            for (int j = 0; j < chunk; ++j) {
                int b = top - j;
                if (sa + h[b] > P) { cb = b; break; }
                sa += h[b];
            }
            *outCb = cb; *outSa = sa;
        }
    }
}

__global__ __launch_bounds__(1024) void sample_kernel(
        float* __restrict__ probs, const float* __restrict__ temps,
        const float* __restrict__ topps, float* __restrict__ outTok) {
    const int row = blockIdx.x;
    const int tid = (int)threadIdx.x;
    float* L = probs + (long long)row * VOCAB;
    const float4* L4 = (const float4*)L;
    float4* L4w = (float4*)L;

    __shared__ float waveH[16][2048];
    __shared__ float hsum[2048];
    __shared__ uint32_t hcnt[1024];
    __shared__ float wred[16];
    __shared__ float aVal[16];
    __shared__ int aIdx[16];
    __shared__ uint32_t tieList[256];
    __shared__ int sCb;
    __shared__ float sSa;
    __shared__ float sP, sCarry1, sCarry2, sSp, sInvSp;
    __shared__ uint32_t sPref1, sCb2, sTsKey, sMt, sTieN, sCnt;
    uint32_t* keys = (uint32_t*)&waveH[4][0];

    const float t = temps[row];
    const float p = topps[row];
    const float rinv = 1.0f / t;

    for (int i = tid; i < 16 * 2048; i += 1024) ((float*)waveH)[i] = 0.0f;
    __syncthreads();
    {
        float* myH = waveH[tid >> 6];
#pragma unroll 2
        for (int i = 0; i < 31; ++i) {
            float4 x = L4[tid + i * 1024];
            float r0 = rv_of(x.x, rinv), r1 = rv_of(x.y, rinv);
            float r2 = rv_of(x.z, rinv), r3 = rv_of(x.w, rinv);
            atomicAdd(&myH[__float_as_uint(r0) >> 20], r0);
            atomicAdd(&myH[__float_as_uint(r1) >> 20], r1);
            atomicAdd(&myH[__float_as_uint(r2) >> 20], r2);
            atomicAdd(&myH[__float_as_uint(r3) >> 20], r3);
        }
        if (tid < 256) {
            float4 x = L4[31744 + tid];
            float r0 = rv_of(x.x, rinv), r1 = rv_of(x.y, rinv);
            float r2 = rv_of(x.z, rinv), r3 = rv_of(x.w, rinv);
            atomicAdd(&myH[__float_as_uint(r0) >> 20], r0);
            atomicAdd(&myH[__float_as_uint(r1) >> 20], r1);
            atomicAdd(&myH[__float_as_uint(r2) >> 20], r2);
            atomicAdd(&myH[__float_as_uint(r3) >> 20], r3);
        }
    }
    __syncthreads();
    {
        float a0 = 0.0f, a1 = 0.0f;
#pragma unroll
        for (int w2 = 0; w2 < 16; ++w2) { a0 += waveH[w2][tid]; a1 += waveH[w2][tid + 1024]; }
        hsum[tid] = a0; hsum[tid + 1024] = a1;
        float s = a0 + a1;
        for (int o = 32; o >= 1; o >>= 1) s += __shfl_xor(s, o, 64);
        if ((tid & 63) == 0) wred[tid >> 6] = s;
    }
    __syncthreads();
    if (tid == 0) {
        float tot = 0.0f;
        for (int w2 = 0; w2 < 16; ++w2) tot += wred[w2];
        sP = p * tot;
    }
    __syncthreads();
    if (tid < 64) scan_desc_wave(hsum, 2048, 0.0f, sP, &sCb, &sSa);
    __syncthreads();
    if (tid == 0) { sPref1 = (uint32_t)sCb; sCarry1 = sSa; sCnt = 0u; }
    __syncthreads();

    const uint32_t pref1 = sPref1;
    const float P = sP;
#pragma unroll 2
    for (int i = 0; i < 31; ++i) {
        float4 x = L4[tid + i * 1024];
        float rr[4] = {rv_of(x.x, rinv), rv_of(x.y, rinv), rv_of(x.z, rinv), rv_of(x.w, rinv)};
#pragma unroll
        for (int c = 0; c < 4; ++c) {
            uint32_t key = __float_as_uint(rr[c]);
            if ((key >> 20) == pref1) {
                uint32_t pos = atomicAdd(&sCnt, 1u);
                if (pos < LIST_CAP) keys[pos] = key;
            }
        }
    }
    if (tid < 256) {
        float4 x = L4[31744 + tid];
        float rr[4] = {rv_of(x.x, rinv), rv_of(x.y, rinv), rv_of(x.z, rinv), rv_of(x.w, rinv)};
#pragma unroll
        for (int c = 0; c < 4; ++c) {
            uint32_t key = __float_as_uint(rr[c]);
            if ((key >> 20) == pref1) {
                uint32_t pos = atomicAdd(&sCnt, 1u);
                if (pos < LIST_CAP) keys[pos] = key;
            }
        }
    }
    __syncthreads();
    const uint32_t K = sCnt;
    const bool inLds = (K <= LIST_CAP);

    if (tid < 1024) hsum[tid] = 0.0f;
    __syncthreads();
    if (inLds) {
        for (uint32_t j = tid; j < K; j += 1024) {
            uint32_t key = keys[j];
            atomicAdd(&hsum[(key >> 10) & 1023u], __uint_as_float(key));
        }
    } else {
        for (int i = 0; i < 125; ++i) {
            int v = tid + i * 1024;
            float rv = rv_of(L[v], rinv);
            uint32_t key = __float_as_uint(rv);
            if ((key >> 20) == pref1) atomicAdd(&hsum[(key >> 10) & 1023u], rv);
        }
    }
    __syncthreads();
    if (tid < 64) scan_desc_wave(hsum, 1024, sCarry1, P, &sCb, &sSa);
    __syncthreads();
    if (tid == 0) { sCb2 = (uint32_t)sCb; sCarry2 = sSa; }
    __syncthreads();

    const uint32_t cb2 = sCb2;
    if (tid < 1024) { hsum[tid] = 0.0f; hcnt[tid] = 0u; }
    __syncthreads();
    if (inLds) {
        for (uint32_t j = tid; j < K; j += 1024) {
            uint32_t key = keys[j];
            if (((key >> 10) & 1023u) == cb2) {
                atomicAdd(&hsum[key & 1023u], __uint_as_float(key));
                atomicAdd(&hcnt[key & 1023u], 1u);
            }
        }
    } else {
        const uint32_t pref2full = (pref1 << 10) | cb2;
        for (int i = 0; i < 125; ++i) {
            int v = tid + i * 1024;
            float rv = rv_of(L[v], rinv);
            uint32_t key = __float_as_uint(rv);
            if ((key >> 10) == pref2full) {
                atomicAdd(&hsum[key & 1023u], rv);
                atomicAdd(&hcnt[key & 1023u], 1u);
            }
        }
    }
    __syncthreads();
    if (tid < 64) scan_desc_wave(hsum, 1024, sCarry2, P, &sCb, &sSa);
    __syncthreads();
    if (tid == 0) {
        int cb3 = sCb; float sa3 = sSa;
        uint32_t ts = (pref1 << 20) | (cb2 << 10) | (uint32_t)cb3;
        uint32_t cnt = hcnt[cb3]; if (cnt == 0u) cnt = 1u;
        float tf = __uint_as_float(ts);
        uint32_t mt;
        float rem = P - sa3; if (rem < 0.0f) rem = 0.0f;
        if (!(tf > 0.0f)) mt = cnt;
        else {
            float q = floorf(rem / tf);
            mt = (q >= (float)(cnt - 1)) ? cnt : ((uint32_t)q + 1u);
        }
        sTsKey = ts; sMt = mt;
        sSp = sa3 + (float)mt * tf;
        sInvSp = 1.0f / sSp;
        sTieN = 0u;
    }
    __syncthreads();

    const uint32_t ts = sTsKey, mt = sMt;
    const float invSp = sInvSp;
    float bestV = -INFINITY;
    int bestI = 0x7FFFFFFF;
    const uint32_t rowBase = (uint32_t)row * (uint32_t)VOCAB;
    for (int i = 0; i < 32; ++i) {
        int f4i = (i < 31) ? (tid + i * 1024) : (31744 + tid);
        if (i == 31 && tid >= 256) break;
        float4 x = L4[f4i];
        float rr[4] = {rv_of(x.x, rinv), rv_of(x.y, rinv), rv_of(x.z, rinv), rv_of(x.w, rinv)};
        float4 out;
        float* op = (float*)&out;
#pragma unroll
        for (int c = 0; c < 4; ++c) {
            uint32_t key = __float_as_uint(rr[c]);
            int v = f4i * 4 + c;
            if (key > ts) {
                float pf = rr[c] * invSp;
                op[c] = pf;
                float g = jax_gumbel(jax_bits(rowBase + (uint32_t)v));
                float val = __logf(pf + 1e-20f) + g;
                if (val > bestV || (val == bestV && v < bestI)) { bestV = val; bestI = v; }
            } else if (key == ts) {
                op[c] = 0.0f;
                uint32_t pos = atomicAdd(&sTieN, 1u);
                if (pos < 256u) tieList[pos] = (uint32_t)v;
            } else {
                op[c] = 0.0f;
            }
        }
        L4w[f4i] = out;
    }
    __syncthreads();
    {
        const uint32_t tn = min(sTieN, 256u);
        if ((uint32_t)tid < tn) {
            uint32_t v = tieList[tid];
            uint32_t rank = 0;
            for (uint32_t j = 0; j < tn; ++j) rank += (tieList[j] < v) ? 1u : 0u;
            if (rank < mt) {
                float pf = __uint_as_float(ts) * invSp;
                L[v] = pf;
                float g = jax_gumbel(jax_bits(rowBase + v));
                float val = __logf(pf + 1e-20f) + g;
                if (val > bestV || (val == bestV && (int)v < bestI)) { bestV = val; bestI = (int)v; }
            }
        }
    }
    for (int o = 32; o >= 1; o >>= 1) {
        float ov = __shfl_xor(bestV, o, 64);
        int oi = __shfl_xor(bestI, o, 64);
        if (ov > bestV || (ov == bestV && oi < bestI)) { bestV = ov; bestI = oi; }
    }
    if ((tid & 63) == 0) { aVal[tid >> 6] = bestV; aIdx[tid >> 6] = bestI; }
    __syncthreads();
    if (tid == 0) {
        float bv = aVal[0]; int bi = aIdx[0];
        for (int w2 = 1; w2 < 16; ++w2) {
            if (aVal[w2] > bv || (aVal[w2] == bv && aIdx[w2] < bi)) { bv = aVal[w2]; bi = aIdx[w2]; }
        }
        outTok[row] = (float)bi;
    }
}

// ===================== launch =====================
extern "C" void kernel_launch(void* const* d_in, const int* in_sizes, int n_in,
                              void* d_out, int out_size, void* d_ws, size_t ws_size,
                              hipStream_t stream) {
    const float* hidden = (const float*)d_in[0];
    const float* emb    = (const float*)d_in[1];
    const float* temps  = (const float*)d_in[2];
    const float* topps  = (const float*)d_in[3];
    const int*   idx    = (const int*)d_in[4];

    float* probs  = (float*)d_out;        // [N,V]: logits, then probs_f in place
    float* outTok = probs + NV_ELEMS;     // [N] tokens as f32

    char* ws = (char*)d_ws;
    const bool wsGemm = ws_size >= (size_t)(1u << 20);
    const bool wsBig  = ws_size >= (size_t)(4u << 20);

    if (wsGemm) {
        ushort* wsA = (ushort*)ws;        // 32 x 32 KB pre-swizzled A images
        prep_a<<<N_TOK, 256, 0, stream>>>(hidden, idx, wsA);
        gemm_mfma<<<VOCAB / 64, 256, 0, stream>>>(wsA, emb, probs);
    } else {
        gemm_kernel<<<dim3(4, 2000), 256, 0, stream>>>(hidden, idx, emb, probs);
    }

    if (wsBig) {
        char* m        = ws + (2u << 20);
        u32* scTs      = (u32*)(m);                 // 1 KB
        u32* scTieN    = (u32*)(m + 1024);          // 1 KB
        float* scInvSp = (float*)(m + 2048);        // 1 KB
        u64* argmax    = (u64*)(m + 3072);          // 2 KB
        u32* tieKept   = (u32*)(m + 8192);          // 1 MB

        resolveC_kernel<<<N_TOK, 1024, 0, stream>>>(probs, temps, topps,
                                                    scTs, scTieN, scInvSp,
                                                    tieKept, argmax);
        final2_kernel<<<dim3(4, N_TOK), 512, 0, stream>>>(probs, temps, scTs, scTieN,
                                                          scInvSp, tieKept, argmax);
        token_kernel<<<1, 256, 0, stream>>>(argmax, outTok);
    } else {
        sample_kernel<<<N_TOK, 1024, 0, stream>>>(probs, temps, topps, outTok);
    }
}